// Round 8
// baseline (366.299 us; speedup 1.0000x reference)
//
#include <hip/hip_runtime.h>
#include <hip/hip_bf16.h>

#define EMB 1024
#define SEQ 2048
#define BATCH 2
#define HEADS 16
#define HDIM 64
#define ROWS (BATCH*SEQ)   // 4096

typedef __hip_bfloat16 bf16;
typedef __bf16 bf16x8 __attribute__((ext_vector_type(8)));
typedef float f32x4 __attribute__((ext_vector_type(4)));

#define AS1 __attribute__((address_space(1)))
#define AS3 __attribute__((address_space(3)))

__device__ __forceinline__ void load_lds16(const void* g, void* l) {
    __builtin_amdgcn_global_load_lds((const AS1 void*)g, (AS3 void*)l, 16, 0, 0);
}

// gelu_tanh(x) == x * sigmoid(2c(x + 0.044715 x^3)), c = sqrt(2/pi)
__device__ __forceinline__ float gelu_f(float x) {
    float y = 1.5957691216057308f * (x + 0.044715f * x * x * x);
    return x / (1.0f + __expf(-y));
}

// ---------------- transpose+cast: in[R][C] (f32) -> out[C][R] (bf16) ----------------
__global__ void transpose_cast_kernel(const float* __restrict__ in, bf16* __restrict__ out,
                                      int R, int C) {
    __shared__ bf16 tile[32][33];
    int tx = threadIdx.x, ty = threadIdx.y;
    int c0 = blockIdx.x * 32, r0 = blockIdx.y * 32;
    for (int i = ty; i < 32; i += 8)
        tile[i][tx] = (bf16)in[(size_t)(r0 + i) * C + c0 + tx];
    __syncthreads();
    for (int i = ty; i < 32; i += 8)
        out[(size_t)(c0 + i) * R + r0 + tx] = tile[tx][i];
}

// batched 1024x1024 transpose+cast for the 4 square weights (one launch)
__global__ void transpose_cast4_kernel(const float* __restrict__ w0, const float* __restrict__ w1,
                                       const float* __restrict__ w2, const float* __restrict__ w3,
                                       bf16* __restrict__ o0, bf16* __restrict__ o1,
                                       bf16* __restrict__ o2, bf16* __restrict__ o3) {
    __shared__ bf16 tile[32][33];
    int z = blockIdx.z;
    const float* in = (z == 0) ? w0 : (z == 1) ? w1 : (z == 2) ? w2 : w3;
    bf16* out = (z == 0) ? o0 : (z == 1) ? o1 : (z == 2) ? o2 : o3;
    int tx = threadIdx.x, ty = threadIdx.y;
    int c0 = blockIdx.x * 32, r0 = blockIdx.y * 32;
    for (int i = ty; i < 32; i += 8)
        tile[i][tx] = (bf16)in[(size_t)(r0 + i) * 1024 + c0 + tx];
    __syncthreads();
    for (int i = ty; i < 32; i += 8)
        out[(size_t)(c0 + i) * 1024 + r0 + tx] = tile[tx][i];
}

// ---------------- per-head V transpose: v[b][s][h*64+d] -> vt[(b*16+h)][d][s] (bf16) ----------------
__global__ void transpose_v_kernel(const bf16* __restrict__ v, bf16* __restrict__ vt) {
    __shared__ bf16 tile[32][33];
    int tx = threadIdx.x, ty = threadIdx.y;
    int bh = blockIdx.z;
    const bf16* in = v + (size_t)(bh >> 4) * SEQ * EMB + (bh & 15) * HDIM;
    bf16* out = vt + (size_t)bh * HDIM * SEQ;
    int s0 = blockIdx.x * 32, d0 = blockIdx.y * 32;
    for (int i = ty; i < 32; i += 8)
        tile[i][tx] = in[(size_t)(s0 + i) * EMB + d0 + tx];
    __syncthreads();
    for (int i = ty; i < 32; i += 8)
        out[(size_t)(d0 + i) * SEQ + s0 + tx] = tile[tx][i];
}

// ---------------- layernorm (ddof=1): f32 in, bf16 out, f32 stats ----------------
__global__ __launch_bounds__(256) void layernorm_kernel(const float* __restrict__ x,
                                                        bf16* __restrict__ out,
                                                        const float* __restrict__ scale,
                                                        const float* __restrict__ shift) {
    int row = blockIdx.x;
    int t = threadIdx.x;
    const float* xr = x + (size_t)row * EMB;
    float v[4];
    float s = 0.f, s2 = 0.f;
#pragma unroll
    for (int i = 0; i < 4; i++) {
        v[i] = xr[t + 256 * i];
        s += v[i];
        s2 += v[i] * v[i];
    }
#pragma unroll
    for (int off = 32; off > 0; off >>= 1) {
        s += __shfl_down(s, off);
        s2 += __shfl_down(s2, off);
    }
    __shared__ float sh[8];
    __shared__ float stats[2];
    int lane = t & 63, wid = t >> 6;
    if (lane == 0) { sh[wid] = s; sh[wid + 4] = s2; }
    __syncthreads();
    if (t == 0) {
        float ts = sh[0] + sh[1] + sh[2] + sh[3];
        float ts2 = sh[4] + sh[5] + sh[6] + sh[7];
        float mean = ts / (float)EMB;
        float var = (ts2 - (float)EMB * mean * mean) / (float)(EMB - 1);
        stats[0] = mean;
        stats[1] = rsqrtf(var + 1e-5f);
    }
    __syncthreads();
    float mean = stats[0], inv = stats[1];
#pragma unroll
    for (int i = 0; i < 4; i++) {
        int c = t + 256 * i;
        float y = (v[i] - mean) * inv * scale[c] + shift[c];
        out[(size_t)row * EMB + c] = (bf16)y;
    }
}

// ---------------- 128x64 GEMM, BK=64 (2x32 halves), double-buffered ----------------
// The pipeline's proven GEMM structure (R7): 2-phase staging, 16 MFMA per barrier,
// 48 KB LDS -> 3 blocks/CU resident. 4 waves each own a 64x32 quadrant.
// M fixed 4096 (32 row-panels, 4/XCD via swizzle). Grid = 32 * (N/64).
// QKV==1: 3-way split epilogue (q/k/v regions, 0.125 scale on q); each 64-col
// tile lies in exactly one 1024-aligned region.
template <int ACT, int QKV, int RES, int OUTF>
__global__ __launch_bounds__(256) void gemm12864_kernel(const bf16* __restrict__ A,
                                                        const bf16* __restrict__ BT,
                                                        void* __restrict__ C0,
                                                        void* __restrict__ C1,
                                                        void* __restrict__ C2,
                                                        const float* __restrict__ bias0,
                                                        const float* __restrict__ bias1,
                                                        const float* __restrict__ bias2,
                                                        const float* __restrict__ res,
                                                        int N, int K) {
    __shared__ __align__(16) bf16 lA[2][2][128 * 32];  // [buf][k-half][row][col]
    __shared__ __align__(16) bf16 lB[2][2][64 * 32];
    int tid = threadIdx.x;
    int wave = tid >> 6, lane = tid & 63;
    int id = blockIdx.x;
    int xcd = id & 7, m = id >> 3;
    int by = xcd + 8 * (m & 3);      // 0..31 (4 M-panels per XCD)
    int bx = m >> 2;                 // 0..N/64-1
    int m0 = by * 128, n0 = bx * 64;
    int wm = (wave >> 1) * 64, wn = (wave & 1) * 32;
    f32x4 acc[4][2] = {};

    int srow = wave * 16 + (lane >> 2);   // 0..63
    int skc = (lane & 3) * 8;
    const bf16* Ag = A + (size_t)(m0 + srow) * K + skc;
    const bf16* Bg = BT + (size_t)(n0 + srow) * K + skc;
    size_t woff = (size_t)(wave * 16) * 32;   // elems; linear per-lane inside wave

    const int an = lane & 15;
    const int ak = (lane >> 4) * 8;
    const size_t rowK64 = (size_t)64 * K;

    // prologue: step 0 (6 loads/thread)
    load_lds16(Ag, &lA[0][0][woff]);
    load_lds16(Ag + rowK64, &lA[0][0][woff + 64 * 32]);
    load_lds16(Ag + 32, &lA[0][1][woff]);
    load_lds16(Ag + rowK64 + 32, &lA[0][1][woff + 64 * 32]);
    load_lds16(Bg, &lB[0][0][woff]);
    load_lds16(Bg + 32, &lB[0][1][woff]);

    int nsteps = K >> 6;
    for (int t = 0; t < nsteps; t++) {
        int buf = t & 1;
        asm volatile("s_waitcnt vmcnt(0)" ::: "memory");
        __syncthreads();
        if (t + 1 < nsteps) {
            int k0 = (t + 1) * 64;
            load_lds16(Ag + k0, &lA[buf ^ 1][0][woff]);
            load_lds16(Ag + rowK64 + k0, &lA[buf ^ 1][0][woff + 64 * 32]);
            load_lds16(Ag + k0 + 32, &lA[buf ^ 1][1][woff]);
            load_lds16(Ag + rowK64 + k0 + 32, &lA[buf ^ 1][1][woff + 64 * 32]);
            load_lds16(Bg + k0, &lB[buf ^ 1][0][woff]);
            load_lds16(Bg + k0 + 32, &lB[buf ^ 1][1][woff]);
        }
#pragma unroll
        for (int h = 0; h < 2; h++) {
            bf16x8 af[4], bfv[2];
#pragma unroll
            for (int i = 0; i < 4; i++)
                af[i] = *(const bf16x8*)(&lA[buf][h][(wm + 16 * i + an) * 32 + ak]);
#pragma unroll
            for (int j = 0; j < 2; j++)
                bfv[j] = *(const bf16x8*)(&lB[buf][h][(wn + 16 * j + an) * 32 + ak]);
#pragma unroll
            for (int i = 0; i < 4; i++)
#pragma unroll
                for (int j = 0; j < 2; j++)
                    acc[i][j] = __builtin_amdgcn_mfma_f32_16x16x32_bf16(af[i], bfv[j], acc[i][j], 0, 0, 0);
        }
    }
#pragma unroll
    for (int j = 0; j < 2; j++) {
        int col = n0 + wn + 16 * j + an;
        if (QKV == 0) {
            float bv = bias0[col];
#pragma unroll
            for (int i = 0; i < 4; i++) {
#pragma unroll
                for (int r = 0; r < 4; r++) {
                    int row = m0 + wm + 16 * i + (lane >> 4) * 4 + r;
                    float vx = acc[i][j][r] + bv;
                    if (ACT == 1) vx = gelu_f(vx);
                    size_t idx = (size_t)row * N + col;
                    if (RES == 2) vx += res[idx];
                    if (OUTF == 0) ((bf16*)C0)[idx] = (bf16)vx;
                    else ((float*)C0)[idx] = vx;
                }
            }
        } else {
            int region = col >> 10, c = col & 1023;
            const float* bp = (region == 0) ? bias0 : (region == 1) ? bias1 : bias2;
            bf16* outp = (region == 0) ? (bf16*)C0 : (region == 1) ? (bf16*)C1 : (bf16*)C2;
            float scl = (region == 0) ? 0.125f : 1.0f;
            float bv = bp[c];
#pragma unroll
            for (int i = 0; i < 4; i++) {
#pragma unroll
                for (int r = 0; r < 4; r++) {
                    int row = m0 + wm + 16 * i + (lane >> 4) * 4 + r;
                    float vx = (acc[i][j][r] + bv) * scl;
                    outp[(size_t)row * EMB + c] = (bf16)vx;
                }
            }
        }
    }
}

// ---------------- causal flash attention, KVBLK=64, XOR-swizzled LDS ----------------
// NOTE: exp via __expf (compiler-generated v_exp handles the TRANS-use hazard;
// raw inline-asm v_exp_f32 produced stale-register reads -> R2 failure).
__global__ __launch_bounds__(256, 4) void attn_kernel(const bf16* __restrict__ q,
                                                      const bf16* __restrict__ k,
                                                      const bf16* __restrict__ vt,
                                                      bf16* __restrict__ ctx) {
    __shared__ __align__(16) bf16 ksm[2][64 * 64];
    __shared__ __align__(16) bf16 vsm[2][64 * 64];
    __shared__ __align__(16) bf16 pbuf[4][16][40];   // per-wave P half-tile (32 kv)
    int tid = threadIdx.x;
    int wave = tid >> 6, lane = tid & 63;
    int id = blockIdx.x;
    int bh = id >> 5;
    int bx = ((id & 31) + bh) & 31;
    int b = bh >> 4, h = bh & 15;
    int q0 = bx * 64 + wave * 16;
    const bf16* qp = q + (size_t)b * SEQ * EMB + h * HDIM;
    const bf16* kp = k + (size_t)b * SEQ * EMB + h * HDIM;
    const bf16* vp = vt + (size_t)bh * HDIM * SEQ;

    int an = lane & 15, aq = lane >> 4;

    bf16x8 qf0 = *(const bf16x8*)(qp + (size_t)(q0 + an) * EMB + aq * 8);
    bf16x8 qf1 = *(const bf16x8*)(qp + (size_t)(q0 + an) * EMB + 32 + aq * 8);
    f32x4 o[4] = {};
    float lp[4] = {0.f, 0.f, 0.f, 0.f};

    int srow0 = tid >> 3;           // 0..31
    int srow1 = srow0 + 32;         // 32..63
    int sc = tid & 7;
    const bf16* kg0 = kp + (size_t)srow0 * EMB + ((sc ^ (srow0 & 7)) * 8);
    const bf16* kg1 = kp + (size_t)srow1 * EMB + ((sc ^ (srow1 & 7)) * 8);
    const bf16* vg0 = vp + (size_t)srow0 * SEQ + ((sc ^ (srow0 & 7)) * 8);
    const bf16* vg1 = vp + (size_t)srow1 * SEQ + ((sc ^ (srow1 & 7)) * 8);

    int nsteps = bx + 1;

    load_lds16(kg0, ksm[0] + tid * 8);
    load_lds16(kg1, ksm[0] + (256 + tid) * 8);
    load_lds16(vg0, vsm[0] + tid * 8);
    load_lds16(vg1, vsm[0] + (256 + tid) * 8);
    asm volatile("s_waitcnt vmcnt(0)" ::: "memory");
    __syncthreads();

    auto step = [&](int t, bool last_) {
        int buf = t & 1;
        if (!last_) {
            size_t ko = (size_t)(t + 1) * 64 * EMB;
            int vo = (t + 1) * 64;
            load_lds16(kg0 + ko, ksm[buf ^ 1] + tid * 8);
            load_lds16(kg1 + ko, ksm[buf ^ 1] + (256 + tid) * 8);
            load_lds16(vg0 + vo, vsm[buf ^ 1] + tid * 8);
            load_lds16(vg1 + vo, vsm[buf ^ 1] + (256 + tid) * 8);
        }
        const bf16* kb = ksm[buf];
        const bf16* vb = vsm[buf];
        int kvbase = t * 64;
#pragma unroll
        for (int hh = 0; hh < 2; hh++) {
#pragma unroll
            for (int nbl = 0; nbl < 2; nbl++) {
                int nb = hh * 2 + nbl;
                int krow = nb * 16 + an;
                bf16x8 kfa = *(const bf16x8*)(kb + krow * 64 + ((aq ^ (an & 7)) * 8));
                bf16x8 kfb = *(const bf16x8*)(kb + krow * 64 + (((4 + aq) ^ (an & 7)) * 8));
                f32x4 s = {};
                s = __builtin_amdgcn_mfma_f32_16x16x32_bf16(qf0, kfa, s, 0, 0, 0);
                s = __builtin_amdgcn_mfma_f32_16x16x32_bf16(qf1, kfb, s, 0, 0, 0);
                int kvg = kvbase + nb * 16 + an;
#pragma unroll
                for (int r = 0; r < 4; r++) {
                    float p = __expf(s[r]);
                    if (last_ && (kvg > q0 + aq * 4 + r)) p = 0.f;
                    lp[r] += p;
                    pbuf[wave][aq * 4 + r][nbl * 16 + an] = (bf16)p;
                }
            }
            asm volatile("s_waitcnt lgkmcnt(0)" ::: "memory");
            bf16x8 pa = *(const bf16x8*)(&pbuf[wave][an][aq * 8]);
#pragma unroll
            for (int dt = 0; dt < 4; dt++) {
                int drow = dt * 16 + an;
                bf16x8 vf = *(const bf16x8*)(vb + drow * 64 + (((hh * 4 + aq) ^ (an & 7)) * 8));
                o[dt] = __builtin_amdgcn_mfma_f32_16x16x32_bf16(pa, vf, o[dt], 0, 0, 0);
            }
        }
        if (!last_) {
            asm volatile("s_waitcnt vmcnt(0)" ::: "memory");
            __syncthreads();
        }
    };

    for (int t = 0; t < nsteps - 1; t++) step(t, false);
    step(nsteps - 1, true);

#pragma unroll
    for (int r = 0; r < 4; r++) {
        float v = lp[r];
        v += __shfl_xor(v, 1);
        v += __shfl_xor(v, 2);
        v += __shfl_xor(v, 4);
        v += __shfl_xor(v, 8);
        lp[r] = v;
    }
#pragma unroll
    for (int dt = 0; dt < 4; dt++) {
#pragma unroll
        for (int r = 0; r < 4; r++) {
            int row = q0 + aq * 4 + r;
            int col = h * HDIM + dt * 16 + an;
            ctx[((size_t)b * SEQ + row) * EMB + col] = (bf16)(o[dt][r] / lp[r]);
        }
    }
}

extern "C" void kernel_launch(void* const* d_in, const int* in_sizes, int n_in,
                              void* d_out, int out_size, void* d_ws, size_t ws_size,
                              hipStream_t stream) {
    const float* x = (const float*)d_in[0];
    const float* Wq = (const float*)d_in[1];
    const float* bq = (const float*)d_in[2];
    const float* Wk = (const float*)d_in[3];
    const float* bk = (const float*)d_in[4];
    const float* Wv = (const float*)d_in[5];
    const float* bv = (const float*)d_in[6];
    const float* Wo = (const float*)d_in[7];
    const float* bo = (const float*)d_in[8];
    const float* W1 = (const float*)d_in[9];
    const float* b1 = (const float*)d_in[10];
    const float* W2 = (const float*)d_in[11];
    const float* b2 = (const float*)d_in[12];
    const float* ln1s = (const float*)d_in[13];
    const float* ln1b = (const float*)d_in[14];
    const float* ln2s = (const float*)d_in[15];
    const float* ln2b = (const float*)d_in[16];
    float* out = (float*)d_out;

    char* ws = (char*)d_ws;
    const size_t MB = 1ull << 20;
    bf16* WqT = (bf16*)(ws + 0 * MB);    // WqT/WkT/WvT contiguous = [3072][1024]
    bf16* WkT = (bf16*)(ws + 2 * MB);
    bf16* WvT = (bf16*)(ws + 4 * MB);
    bf16* WoT = (bf16*)(ws + 6 * MB);
    bf16* W1T = (bf16*)(ws + 8 * MB);    // [4096][1024]
    bf16* W2T = (bf16*)(ws + 16 * MB);   // [1024][4096]
    bf16* hbuf = (bf16*)(ws + 24 * MB);
    bf16* qbuf = (bf16*)(ws + 32 * MB);
    bf16* kbuf = (bf16*)(ws + 40 * MB);
    bf16* vbuf = (bf16*)(ws + 48 * MB);
    bf16* vtb = (bf16*)(ws + 56 * MB);
    bf16* ctxb = (bf16*)(ws + 64 * MB);
    float* x1 = (float*)(ws + 72 * MB);  // fp32 residual, 16MB
    bf16* hff = (bf16*)(ws + 32 * MB);   // overlaps q/k/v/vt (dead by FFN)

    dim3 tb(32, 8);
    transpose_cast4_kernel<<<dim3(32, 32, 4), tb, 0, stream>>>(Wq, Wk, Wv, Wo, WqT, WkT, WvT, WoT);
    transpose_cast_kernel<<<dim3(128, 32), tb, 0, stream>>>(W1, W1T, 1024, 4096);
    transpose_cast_kernel<<<dim3(32, 128), tb, 0, stream>>>(W2, W2T, 4096, 1024);

    layernorm_kernel<<<ROWS, 256, 0, stream>>>(x, hbuf, ln1s, ln1b);

    // fused QKV: 128x64 2-phase tiles, N=3072 -> grid 1536
    gemm12864_kernel<0, 1, 0, 0><<<1536, 256, 0, stream>>>(
        hbuf, WqT, qbuf, kbuf, vbuf, bq, bk, bv, nullptr, 3 * EMB, EMB);

    transpose_v_kernel<<<dim3(64, 2, 32), tb, 0, stream>>>(vbuf, vtb);

    attn_kernel<<<1024, 256, 0, stream>>>(qbuf, kbuf, vtb, ctxb);

    // x1 = x + ctx @ Wo + bo   (f32 out, f32 residual) — grid 512
    gemm12864_kernel<0, 0, 2, 1><<<512, 256, 0, stream>>>(
        ctxb, WoT, x1, nullptr, nullptr, bo, nullptr, nullptr, x, EMB, EMB);

    layernorm_kernel<<<ROWS, 256, 0, stream>>>(x1, hbuf, ln2s, ln2b);

    // hff = gelu(h2 @ W1 + b1) — N=4096 -> grid 2048
    gemm12864_kernel<1, 0, 0, 0><<<2048, 256, 0, stream>>>(
        hbuf, W1T, hff, nullptr, nullptr, b1, nullptr, nullptr, nullptr, 4 * EMB, EMB);

    // out = x1 + hff @ W2 + b2 — K=4096, grid 512
    gemm12864_kernel<0, 0, 2, 1><<<512, 256, 0, stream>>>(
        hff, W2T, out, nullptr, nullptr, b2, nullptr, nullptr, x1, EMB, 4 * EMB);
}

// Round 9
// 360.986 us; speedup vs baseline: 1.0147x; 1.0147x over previous
//
#include <hip/hip_runtime.h>
#include <hip/hip_bf16.h>

#define EMB 1024
#define SEQ 2048
#define BATCH 2
#define HEADS 16
#define HDIM 64
#define ROWS (BATCH*SEQ)   // 4096

typedef __hip_bfloat16 bf16;
typedef __bf16 bf16x8 __attribute__((ext_vector_type(8)));
typedef float f32x4 __attribute__((ext_vector_type(4)));

#define AS1 __attribute__((address_space(1)))
#define AS3 __attribute__((address_space(3)))

__device__ __forceinline__ void load_lds16(const void* g, void* l) {
    __builtin_amdgcn_global_load_lds((const AS1 void*)g, (AS3 void*)l, 16, 0, 0);
}

// gelu_tanh(x) == x * sigmoid(2c(x + 0.044715 x^3)), c = sqrt(2/pi)
__device__ __forceinline__ float gelu_f(float x) {
    float y = 1.5957691216057308f * (x + 0.044715f * x * x * x);
    return x / (1.0f + __expf(-y));
}

// ---------------- transpose+cast: in[R][C] (f32) -> out[C][R] (bf16) ----------------
__global__ void transpose_cast_kernel(const float* __restrict__ in, bf16* __restrict__ out,
                                      int R, int C) {
    __shared__ bf16 tile[32][33];
    int tx = threadIdx.x, ty = threadIdx.y;
    int c0 = blockIdx.x * 32, r0 = blockIdx.y * 32;
    for (int i = ty; i < 32; i += 8)
        tile[i][tx] = (bf16)in[(size_t)(r0 + i) * C + c0 + tx];
    __syncthreads();
    for (int i = ty; i < 32; i += 8)
        out[(size_t)(c0 + i) * R + r0 + tx] = tile[tx][i];
}

// batched 1024x1024 transpose+cast for the 4 square weights (one launch)
__global__ void transpose_cast4_kernel(const float* __restrict__ w0, const float* __restrict__ w1,
                                       const float* __restrict__ w2, const float* __restrict__ w3,
                                       bf16* __restrict__ o0, bf16* __restrict__ o1,
                                       bf16* __restrict__ o2, bf16* __restrict__ o3) {
    __shared__ bf16 tile[32][33];
    int z = blockIdx.z;
    const float* in = (z == 0) ? w0 : (z == 1) ? w1 : (z == 2) ? w2 : w3;
    bf16* out = (z == 0) ? o0 : (z == 1) ? o1 : (z == 2) ? o2 : o3;
    int tx = threadIdx.x, ty = threadIdx.y;
    int c0 = blockIdx.x * 32, r0 = blockIdx.y * 32;
    for (int i = ty; i < 32; i += 8)
        tile[i][tx] = (bf16)in[(size_t)(r0 + i) * 1024 + c0 + tx];
    __syncthreads();
    for (int i = ty; i < 32; i += 8)
        out[(size_t)(c0 + i) * 1024 + r0 + tx] = tile[tx][i];
}

// ---------------- per-head V transpose: v[b][s][h*64+d] -> vt[(b*16+h)][d][s] (bf16) ----------------
__global__ void transpose_v_kernel(const bf16* __restrict__ v, bf16* __restrict__ vt) {
    __shared__ bf16 tile[32][33];
    int tx = threadIdx.x, ty = threadIdx.y;
    int bh = blockIdx.z;
    const bf16* in = v + (size_t)(bh >> 4) * SEQ * EMB + (bh & 15) * HDIM;
    bf16* out = vt + (size_t)bh * HDIM * SEQ;
    int s0 = blockIdx.x * 32, d0 = blockIdx.y * 32;
    for (int i = ty; i < 32; i += 8)
        tile[i][tx] = in[(size_t)(s0 + i) * EMB + d0 + tx];
    __syncthreads();
    for (int i = ty; i < 32; i += 8)
        out[(size_t)(d0 + i) * SEQ + s0 + tx] = tile[tx][i];
}

// ---------------- layernorm (ddof=1): f32 in, bf16 out, f32 stats ----------------
__global__ __launch_bounds__(256) void layernorm_kernel(const float* __restrict__ x,
                                                        bf16* __restrict__ out,
                                                        const float* __restrict__ scale,
                                                        const float* __restrict__ shift) {
    int row = blockIdx.x;
    int t = threadIdx.x;
    const float* xr = x + (size_t)row * EMB;
    float v[4];
    float s = 0.f, s2 = 0.f;
#pragma unroll
    for (int i = 0; i < 4; i++) {
        v[i] = xr[t + 256 * i];
        s += v[i];
        s2 += v[i] * v[i];
    }
#pragma unroll
    for (int off = 32; off > 0; off >>= 1) {
        s += __shfl_down(s, off);
        s2 += __shfl_down(s2, off);
    }
    __shared__ float sh[8];
    __shared__ float stats[2];
    int lane = t & 63, wid = t >> 6;
    if (lane == 0) { sh[wid] = s; sh[wid + 4] = s2; }
    __syncthreads();
    if (t == 0) {
        float ts = sh[0] + sh[1] + sh[2] + sh[3];
        float ts2 = sh[4] + sh[5] + sh[6] + sh[7];
        float mean = ts / (float)EMB;
        float var = (ts2 - (float)EMB * mean * mean) / (float)(EMB - 1);
        stats[0] = mean;
        stats[1] = rsqrtf(var + 1e-5f);
    }
    __syncthreads();
    float mean = stats[0], inv = stats[1];
#pragma unroll
    for (int i = 0; i < 4; i++) {
        int c = t + 256 * i;
        float y = (v[i] - mean) * inv * scale[c] + shift[c];
        out[(size_t)row * EMB + c] = (bf16)y;
    }
}

// For gemm64 (TM=TN=64 over M=4096,N=1024): NYB=64, NXB=16, grid=1024.
__device__ __forceinline__ void swz64(int id, int& bx, int& by) {
    int xcd = id & 7, m = id >> 3;
    by = xcd + 8 * (m & 3) + 32 * (m >> 6);
    bx = (m >> 2) & 15;
}

// stage one 128x64 (bf16) half-tile: 512 threads x 2 x 16B, linear LDS dest,
// global source pre-swizzled (inverse of the read-side XOR swizzle)
__device__ __forceinline__ void stage_half(const bf16* g, bf16* lds, int tid, size_t rowK64) {
    load_lds16(g, lds + tid * 8);
    load_lds16(g + rowK64, lds + 4096 + tid * 8);
}

// ---------------- 256x256 deep-pipelined GEMM (8-phase style) ----------------
template <int ACT, int QKV>
__global__ __launch_bounds__(512, 2) void gemm256_kernel(
    const bf16* __restrict__ A, const bf16* __restrict__ BT,
    bf16* __restrict__ C0, bf16* __restrict__ C1, bf16* __restrict__ C2,
    const float* __restrict__ bias0, const float* __restrict__ bias1,
    const float* __restrict__ bias2, int N, int K) {
    __shared__ __align__(16) bf16 lA[4][128 * 64];
    __shared__ __align__(16) bf16 lB[4][128 * 64];
    const int tid = threadIdx.x;
    const int wave = tid >> 6, lane = tid & 63;
    const int an = lane & 15, aq = lane >> 4;
    const int wr = wave >> 2, wc = wave & 3;

    int id = blockIdx.x;
    int xcd = id & 7, m = id >> 3;
    int by = xcd * 2 + (m & 1);
    int bx = m >> 1;
    int m0 = by * 256, n0 = bx * 256;

    const int srow = tid >> 3;                       // 0..63
    const int csw = ((tid & 7) ^ (srow & 7)) * 8;    // swizzled col offset (elems)
    const bf16* Ag = A + (size_t)(m0 + srow) * K + csw;
    const bf16* Bg = BT + (size_t)(n0 + srow) * K + csw;
    const size_t rowK64 = (size_t)64 * K;
    const size_t rowK128 = (size_t)128 * K;

    stage_half(Bg, lB[0], tid, rowK64);
    stage_half(Bg + rowK128, lB[1], tid, rowK64);
    stage_half(Ag, lA[0], tid, rowK64);
    stage_half(Ag + rowK128, lA[1], tid, rowK64);
    stage_half(Bg + 64, lB[2], tid, rowK64);
    stage_half(Bg + rowK128 + 64, lB[3], tid, rowK64);
    asm volatile("s_waitcnt vmcnt(4)" ::: "memory");
    __builtin_amdgcn_s_barrier();

    f32x4 acc[8][4] = {};
    const int NT = K >> 6;
    const int lrB = (wc & 1) * 64;

    for (int t = 0; t < NT; ++t) {
        const bf16* As = lA[(2 * t + wr) & 3];
        const bf16* Bs = lB[(2 * t + (wc >> 1)) & 3];
        bf16x8 bfv[4][2];
#pragma unroll
        for (int p = 0; p < 4; ++p) {
            bf16x8 af[2][2];
            if (p == 0) {
#pragma unroll
                for (int j = 0; j < 4; ++j)
#pragma unroll
                    for (int kk = 0; kk < 2; ++kk) {
                        int r = lrB + 16 * j + an;
                        bfv[j][kk] = *(const bf16x8*)(Bs + r * 64 + ((kk * 4 + aq) ^ (r & 7)) * 8);
                    }
            }
#pragma unroll
            for (int ii = 0; ii < 2; ++ii)
#pragma unroll
                for (int kk = 0; kk < 2; ++kk) {
                    int r = 16 * (2 * p + ii) + an;
                    af[ii][kk] = *(const bf16x8*)(As + r * 64 + ((kk * 4 + aq) ^ (r & 7)) * 8);
                }
            if (p == 0) {
                if (t + 1 < NT)
                    stage_half(Ag + (size_t)(t + 1) * 64, lA[(2 * t + 2) & 3], tid, rowK64);
            } else if (p == 1) {
                if (t + 1 < NT)
                    stage_half(Ag + rowK128 + (size_t)(t + 1) * 64, lA[(2 * t + 3) & 3], tid, rowK64);
            } else if (p == 2) {
                if (t + 2 < NT)
                    stage_half(Bg + (size_t)(t + 2) * 64, lB[(2 * t + 4) & 3], tid, rowK64);
            } else {
                if (t + 2 < NT) {
                    stage_half(Bg + rowK128 + (size_t)(t + 2) * 64, lB[(2 * t + 5) & 3], tid, rowK64);
                    asm volatile("s_waitcnt vmcnt(4)" ::: "memory");
                } else {
                    asm volatile("s_waitcnt vmcnt(0)" ::: "memory");
                }
            }
            __builtin_amdgcn_s_barrier();
            asm volatile("s_waitcnt lgkmcnt(0)" ::: "memory");
            __builtin_amdgcn_s_setprio(1);
#pragma unroll
            for (int ii = 0; ii < 2; ++ii)
#pragma unroll
                for (int j = 0; j < 4; ++j)
#pragma unroll
                    for (int kk = 0; kk < 2; ++kk)
                        acc[2 * p + ii][j] = __builtin_amdgcn_mfma_f32_16x16x32_bf16(
                            af[ii][kk], bfv[j][kk], acc[2 * p + ii][j], 0, 0, 0);
            __builtin_amdgcn_s_setprio(0);
            __builtin_amdgcn_s_barrier();
        }
    }

#pragma unroll
    for (int j = 0; j < 4; ++j) {
        int col = n0 + wc * 64 + 16 * j + an;
        if (QKV == 0) {
            float bv = bias0[col];
#pragma unroll
            for (int i = 0; i < 8; ++i) {
#pragma unroll
                for (int r = 0; r < 4; ++r) {
                    int row = m0 + wr * 128 + 16 * i + aq * 4 + r;
                    float v = acc[i][j][r] + bv;
                    if (ACT == 1) v = gelu_f(v);
                    C0[(size_t)row * N + col] = (bf16)v;
                }
            }
        } else {
            int region = col >> 10, c = col & 1023;
            const float* bp = (region == 0) ? bias0 : (region == 1) ? bias1 : bias2;
            bf16* outp = (region == 0) ? C0 : (region == 1) ? C1 : C2;
            float scl = (region == 0) ? 0.125f : 1.0f;
            float bv = bp[c];
#pragma unroll
            for (int i = 0; i < 8; ++i) {
#pragma unroll
                for (int r = 0; r < 4; ++r) {
                    int row = m0 + wr * 128 + 16 * i + aq * 4 + r;
                    float v = (acc[i][j][r] + bv) * scl;
                    outp[(size_t)row * EMB + c] = (bf16)v;
                }
            }
        }
    }
}

// ---------------- 64x64 GEMM, BK=64, double-buffered, swizzled (M=4096,N=1024) ----------------
template <int RES, int OUTF>
__global__ __launch_bounds__(256) void gemm64_kernel(const bf16* __restrict__ A,
                                                     const bf16* __restrict__ BT,
                                                     void* __restrict__ Cout,
                                                     const float* __restrict__ bias,
                                                     const float* __restrict__ res,
                                                     int M, int N, int K) {
    __shared__ __align__(16) bf16 lA[2][2][64 * 32];   // [buf][k-half][row][col]
    __shared__ __align__(16) bf16 lB[2][2][64 * 32];
    int tid = threadIdx.x;
    int wave = tid >> 6, lane = tid & 63;
    int bx, by;
    swz64(blockIdx.x, bx, by);
    int m0 = by * 64, n0 = bx * 64;
    int wm = (wave >> 1) * 32, wn = (wave & 1) * 32;
    f32x4 acc[2][2] = {};

    int srow = wave * 16 + (lane >> 2);
    int skc = (lane & 3) * 8;
    const bf16* Ag = A + (size_t)(m0 + srow) * K + skc;
    const bf16* Bg = BT + (size_t)(n0 + srow) * K + skc;
    size_t woff = (size_t)(wave * 16) * 32;

    const int an = lane & 15;
    const int ak = (lane >> 4) * 8;

    load_lds16(Ag, &lA[0][0][woff]);
    load_lds16(Ag + 32, &lA[0][1][woff]);
    load_lds16(Bg, &lB[0][0][woff]);
    load_lds16(Bg + 32, &lB[0][1][woff]);

    int nsteps = K >> 6;
    for (int t = 0; t < nsteps; t++) {
        int buf = t & 1;
        asm volatile("s_waitcnt vmcnt(0)" ::: "memory");
        __syncthreads();
        if (t + 1 < nsteps) {
            int k0 = (t + 1) * 64;
            load_lds16(Ag + k0, &lA[buf ^ 1][0][woff]);
            load_lds16(Ag + k0 + 32, &lA[buf ^ 1][1][woff]);
            load_lds16(Bg + k0, &lB[buf ^ 1][0][woff]);
            load_lds16(Bg + k0 + 32, &lB[buf ^ 1][1][woff]);
        }
#pragma unroll
        for (int h = 0; h < 2; h++) {
            bf16x8 af[2], bfv[2];
#pragma unroll
            for (int i = 0; i < 2; i++)
                af[i] = *(const bf16x8*)(&lA[buf][h][(wm + 16 * i + an) * 32 + ak]);
#pragma unroll
            for (int j = 0; j < 2; j++)
                bfv[j] = *(const bf16x8*)(&lB[buf][h][(wn + 16 * j + an) * 32 + ak]);
#pragma unroll
            for (int i = 0; i < 2; i++)
#pragma unroll
                for (int j = 0; j < 2; j++)
                    acc[i][j] = __builtin_amdgcn_mfma_f32_16x16x32_bf16(af[i], bfv[j], acc[i][j], 0, 0, 0);
        }
    }
#pragma unroll
    for (int j = 0; j < 2; j++) {
        int col = n0 + wn + 16 * j + an;
        float bv = bias[col];
#pragma unroll
        for (int i = 0; i < 2; i++) {
#pragma unroll
            for (int r = 0; r < 4; r++) {
                int row = m0 + wm + 16 * i + (lane >> 4) * 4 + r;
                float vx = acc[i][j][r] + bv;
                size_t idx = (size_t)row * N + col;
                if (RES == 2) vx += res[idx];
                if (OUTF == 0) ((bf16*)Cout)[idx] = (bf16)vx;
                else ((float*)Cout)[idx] = vx;
            }
        }
    }
}

// ---------------- causal flash attention, double-Q (128 q-rows/block), KVBLK=64 ----------------
// Two 64-row q-groups share every staged K/V tile: staging & barriers per q-row
// halve, V fragments read once and used by both groups' PV. Grid 512 (2/CU).
// Tail: t=2bx masks group0; t=2bx+1 skips group0, masks group1.
// NOTE: exp via __expf (raw inline-asm v_exp_f32 -> stale reads, R2 failure).
__global__ __launch_bounds__(256, 2) void attn_kernel(const bf16* __restrict__ q,
                                                      const bf16* __restrict__ k,
                                                      const bf16* __restrict__ vt,
                                                      bf16* __restrict__ ctx) {
    __shared__ __align__(16) bf16 ksm[2][64 * 64];
    __shared__ __align__(16) bf16 vsm[2][64 * 64];
    __shared__ __align__(16) bf16 pbuf[2][4][16][40];   // [group][wave][row][kv(padded)]
    int tid = threadIdx.x;
    int wave = tid >> 6, lane = tid & 63;
    int id = blockIdx.x;
    int bh = id >> 4;
    int bx = ((id & 15) + bh) & 15;
    int b = bh >> 4, h = bh & 15;
    int q0 = bx * 128 + wave * 16;            // group0 rows; group1 = q0 + 64
    const bf16* qp = q + (size_t)b * SEQ * EMB + h * HDIM;
    const bf16* kp = k + (size_t)b * SEQ * EMB + h * HDIM;
    const bf16* vp = vt + (size_t)bh * HDIM * SEQ;

    int an = lane & 15, aq = lane >> 4;

    bf16x8 qf[2][2];
#pragma unroll
    for (int g = 0; g < 2; g++) {
        qf[g][0] = *(const bf16x8*)(qp + (size_t)(q0 + 64 * g + an) * EMB + aq * 8);
        qf[g][1] = *(const bf16x8*)(qp + (size_t)(q0 + 64 * g + an) * EMB + 32 + aq * 8);
    }
    f32x4 o[2][4] = {};
    float lp[2][4] = {};

    int srow0 = tid >> 3;           // 0..31
    int srow1 = srow0 + 32;         // 32..63
    int sc = tid & 7;
    const bf16* kg0 = kp + (size_t)srow0 * EMB + ((sc ^ (srow0 & 7)) * 8);
    const bf16* kg1 = kp + (size_t)srow1 * EMB + ((sc ^ (srow1 & 7)) * 8);
    const bf16* vg0 = vp + (size_t)srow0 * SEQ + ((sc ^ (srow0 & 7)) * 8);
    const bf16* vg1 = vp + (size_t)srow1 * SEQ + ((sc ^ (srow1 & 7)) * 8);

    int nsteps = 2 * bx + 2;

    load_lds16(kg0, ksm[0] + tid * 8);
    load_lds16(kg1, ksm[0] + (256 + tid) * 8);
    load_lds16(vg0, vsm[0] + tid * 8);
    load_lds16(vg1, vsm[0] + (256 + tid) * 8);
    asm volatile("s_waitcnt vmcnt(0)" ::: "memory");
    __syncthreads();

    // mode: 0 = both groups full; 1 = g0 masked, g1 full; 2 = g0 skipped, g1 masked
    auto step = [&](int t, int mode) {
        int buf = t & 1;
        if (t + 1 < nsteps) {
            size_t ko = (size_t)(t + 1) * 64 * EMB;
            int vo = (t + 1) * 64;
            load_lds16(kg0 + ko, ksm[buf ^ 1] + tid * 8);
            load_lds16(kg1 + ko, ksm[buf ^ 1] + (256 + tid) * 8);
            load_lds16(vg0 + vo, vsm[buf ^ 1] + tid * 8);
            load_lds16(vg1 + vo, vsm[buf ^ 1] + (256 + tid) * 8);
        }
        const bf16* kb = ksm[buf];
        const bf16* vb = vsm[buf];
        int kvbase = t * 64;
#pragma unroll
        for (int hh = 0; hh < 2; hh++) {
#pragma unroll
            for (int g = 0; g < 2; g++) {
                if (mode == 2 && g == 0) continue;
                bool msk = (mode == 1 && g == 0) || (mode == 2 && g == 1);
#pragma unroll
                for (int nbl = 0; nbl < 2; nbl++) {
                    int nb = hh * 2 + nbl;
                    int krow = nb * 16 + an;
                    bf16x8 kfa = *(const bf16x8*)(kb + krow * 64 + ((aq ^ (an & 7)) * 8));
                    bf16x8 kfb = *(const bf16x8*)(kb + krow * 64 + (((4 + aq) ^ (an & 7)) * 8));
                    f32x4 s = {};
                    s = __builtin_amdgcn_mfma_f32_16x16x32_bf16(qf[g][0], kfa, s, 0, 0, 0);
                    s = __builtin_amdgcn_mfma_f32_16x16x32_bf16(qf[g][1], kfb, s, 0, 0, 0);
                    int kvg = kvbase + nb * 16 + an;
#pragma unroll
                    for (int r = 0; r < 4; r++) {
                        float p = __expf(s[r]);
                        if (msk && (kvg > q0 + 64 * g + aq * 4 + r)) p = 0.f;
                        lp[g][r] += p;
                        pbuf[g][wave][aq * 4 + r][nbl * 16 + an] = (bf16)p;
                    }
                }
            }
            asm volatile("s_waitcnt lgkmcnt(0)" ::: "memory");
            bf16x8 pa0 = *(const bf16x8*)(&pbuf[0][wave][an][aq * 8]);
            bf16x8 pa1 = *(const bf16x8*)(&pbuf[1][wave][an][aq * 8]);
#pragma unroll
            for (int dt = 0; dt < 4; dt++) {
                int drow = dt * 16 + an;
                bf16x8 vf = *(const bf16x8*)(vb + drow * 64 + (((hh * 4 + aq) ^ (an & 7)) * 8));
                if (mode != 2)
                    o[0][dt] = __builtin_amdgcn_mfma_f32_16x16x32_bf16(pa0, vf, o[0][dt], 0, 0, 0);
                o[1][dt] = __builtin_amdgcn_mfma_f32_16x16x32_bf16(pa1, vf, o[1][dt], 0, 0, 0);
            }
        }
        if (t + 1 < nsteps) {
            asm volatile("s_waitcnt vmcnt(0)" ::: "memory");
            __syncthreads();
        }
    };

    for (int t = 0; t < nsteps - 2; t++) step(t, 0);
    step(nsteps - 2, 1);
    step(nsteps - 1, 2);

#pragma unroll
    for (int g = 0; g < 2; g++)
#pragma unroll
        for (int r = 0; r < 4; r++) {
            float v = lp[g][r];
            v += __shfl_xor(v, 1);
            v += __shfl_xor(v, 2);
            v += __shfl_xor(v, 4);
            v += __shfl_xor(v, 8);
            lp[g][r] = v;
        }
#pragma unroll
    for (int g = 0; g < 2; g++)
#pragma unroll
        for (int dt = 0; dt < 4; dt++) {
#pragma unroll
            for (int r = 0; r < 4; r++) {
                int row = q0 + 64 * g + aq * 4 + r;
                int col = h * HDIM + dt * 16 + an;
                ctx[((size_t)b * SEQ + row) * EMB + col] = (bf16)(o[g][dt][r] / lp[g][r]);
            }
        }
}

extern "C" void kernel_launch(void* const* d_in, const int* in_sizes, int n_in,
                              void* d_out, int out_size, void* d_ws, size_t ws_size,
                              hipStream_t stream) {
    const float* x = (const float*)d_in[0];
    const float* Wq = (const float*)d_in[1];
    const float* bq = (const float*)d_in[2];
    const float* Wk = (const float*)d_in[3];
    const float* bk = (const float*)d_in[4];
    const float* Wv = (const float*)d_in[5];
    const float* bv = (const float*)d_in[6];
    const float* Wo = (const float*)d_in[7];
    const float* bo = (const float*)d_in[8];
    const float* W1 = (const float*)d_in[9];
    const float* b1 = (const float*)d_in[10];
    const float* W2 = (const float*)d_in[11];
    const float* b2 = (const float*)d_in[12];
    const float* ln1s = (const float*)d_in[13];
    const float* ln1b = (const float*)d_in[14];
    const float* ln2s = (const float*)d_in[15];
    const float* ln2b = (const float*)d_in[16];
    float* out = (float*)d_out;

    char* ws = (char*)d_ws;
    const size_t MB = 1ull << 20;
    bf16* WqT = (bf16*)(ws + 0 * MB);    // WqT/WkT/WvT contiguous = [3072][1024]
    bf16* WkT = (bf16*)(ws + 2 * MB);
    bf16* WvT = (bf16*)(ws + 4 * MB);
    bf16* WoT = (bf16*)(ws + 6 * MB);
    bf16* W1T = (bf16*)(ws + 8 * MB);    // [4096][1024]
    bf16* W2T = (bf16*)(ws + 16 * MB);   // [1024][4096]
    bf16* hbuf = (bf16*)(ws + 24 * MB);
    bf16* qbuf = (bf16*)(ws + 32 * MB);
    bf16* kbuf = (bf16*)(ws + 40 * MB);
    bf16* vbuf = (bf16*)(ws + 48 * MB);
    bf16* vtb = (bf16*)(ws + 56 * MB);
    bf16* ctxb = (bf16*)(ws + 64 * MB);
    float* x1 = (float*)(ws + 72 * MB);  // fp32 residual, 16MB
    bf16* hff = (bf16*)(ws + 32 * MB);   // overlaps q/k/v/vt (dead by FFN)

    dim3 tb(32, 8);
    transpose_cast4_kernel<<<dim3(32, 32, 4), tb, 0, stream>>>(Wq, Wk, Wv, Wo, WqT, WkT, WvT, WoT);
    transpose_cast_kernel<<<dim3(128, 32), tb, 0, stream>>>(W1, W1T, 1024, 4096);
    transpose_cast_kernel<<<dim3(32, 128), tb, 0, stream>>>(W2, W2T, 4096, 1024);

    layernorm_kernel<<<ROWS, 256, 0, stream>>>(x, hbuf, ln1s, ln1b);

    // fused QKV: 256x256 tiles, N=3072 -> grid 16*12 = 192, deep-pipelined
    gemm256_kernel<0, 1><<<192, 512, 0, stream>>>(hbuf, WqT, qbuf, kbuf, vbuf,
                                                  bq, bk, bv, EMB, EMB);

    transpose_v_kernel<<<dim3(64, 2, 32), tb, 0, stream>>>(vbuf, vtb);

    // double-Q attention: 128 q-rows/block -> grid 512
    attn_kernel<<<512, 256, 0, stream>>>(qbuf, kbuf, vtb, ctxb);

    // x1 = x + ctx @ Wo + bo   (f32 out, f32 residual) — 64x64 tiles, swizzled
    gemm64_kernel<2, 1><<<1024, 256, 0, stream>>>(ctxb, WoT, x1, bo, x, ROWS, EMB, EMB);

    layernorm_kernel<<<ROWS, 256, 0, stream>>>(x1, hbuf, ln2s, ln2b);

    // hff = gelu(h2 @ W1 + b1) — 256x256 tiles, N=4096 -> grid 16*16 = 256
    gemm256_kernel<1, 0><<<256, 512, 0, stream>>>(hbuf, W1T, hff, nullptr, nullptr,
                                                  b1, nullptr, nullptr, 4 * EMB, EMB);

    // out = x1 + hff @ W2 + b2   (f32 out, f32 residual) — 64x64 tiles, swizzled
    gemm64_kernel<2, 1><<<1024, 256, 0, stream>>>(hff, W2T, out, b2, x1, ROWS, EMB, 4 * EMB);
}

// Round 10
// 351.619 us; speedup vs baseline: 1.0417x; 1.0266x over previous
//
#include <hip/hip_runtime.h>
#include <hip/hip_bf16.h>

#define EMB 1024
#define SEQ 2048
#define BATCH 2
#define HEADS 16
#define HDIM 64
#define ROWS (BATCH*SEQ)   // 4096

typedef __hip_bfloat16 bf16;
typedef __bf16 bf16x8 __attribute__((ext_vector_type(8)));
typedef float f32x4 __attribute__((ext_vector_type(4)));

#define AS1 __attribute__((address_space(1)))
#define AS3 __attribute__((address_space(3)))

__device__ __forceinline__ void load_lds16(const void* g, void* l) {
    __builtin_amdgcn_global_load_lds((const AS1 void*)g, (AS3 void*)l, 16, 0, 0);
}

// gelu_tanh(x) == x * sigmoid(2c(x + 0.044715 x^3)), c = sqrt(2/pi)
__device__ __forceinline__ float gelu_f(float x) {
    float y = 1.5957691216057308f * (x + 0.044715f * x * x * x);
    return x / (1.0f + __expf(-y));
}

// ---------------- transpose+cast: in[R][C] (f32) -> out[C][R] (bf16) ----------------
__global__ void transpose_cast_kernel(const float* __restrict__ in, bf16* __restrict__ out,
                                      int R, int C) {
    __shared__ bf16 tile[32][33];
    int tx = threadIdx.x, ty = threadIdx.y;
    int c0 = blockIdx.x * 32, r0 = blockIdx.y * 32;
    for (int i = ty; i < 32; i += 8)
        tile[i][tx] = (bf16)in[(size_t)(r0 + i) * C + c0 + tx];
    __syncthreads();
    for (int i = ty; i < 32; i += 8)
        out[(size_t)(c0 + i) * R + r0 + tx] = tile[tx][i];
}

// batched 1024x1024 transpose+cast for the 4 square weights (one launch)
__global__ void transpose_cast4_kernel(const float* __restrict__ w0, const float* __restrict__ w1,
                                       const float* __restrict__ w2, const float* __restrict__ w3,
                                       bf16* __restrict__ o0, bf16* __restrict__ o1,
                                       bf16* __restrict__ o2, bf16* __restrict__ o3) {
    __shared__ bf16 tile[32][33];
    int z = blockIdx.z;
    const float* in = (z == 0) ? w0 : (z == 1) ? w1 : (z == 2) ? w2 : w3;
    bf16* out = (z == 0) ? o0 : (z == 1) ? o1 : (z == 2) ? o2 : o3;
    int tx = threadIdx.x, ty = threadIdx.y;
    int c0 = blockIdx.x * 32, r0 = blockIdx.y * 32;
    for (int i = ty; i < 32; i += 8)
        tile[i][tx] = (bf16)in[(size_t)(r0 + i) * 1024 + c0 + tx];
    __syncthreads();
    for (int i = ty; i < 32; i += 8)
        out[(size_t)(c0 + i) * 1024 + r0 + tx] = tile[tx][i];
}

// ---------------- per-head V transpose: v[b][s][h*64+d] -> vt[(b*16+h)][d][s] (bf16) ----------------
__global__ void transpose_v_kernel(const bf16* __restrict__ v, bf16* __restrict__ vt) {
    __shared__ bf16 tile[32][33];
    int tx = threadIdx.x, ty = threadIdx.y;
    int bh = blockIdx.z;
    const bf16* in = v + (size_t)(bh >> 4) * SEQ * EMB + (bh & 15) * HDIM;
    bf16* out = vt + (size_t)bh * HDIM * SEQ;
    int s0 = blockIdx.x * 32, d0 = blockIdx.y * 32;
    for (int i = ty; i < 32; i += 8)
        tile[i][tx] = in[(size_t)(s0 + i) * EMB + d0 + tx];
    __syncthreads();
    for (int i = ty; i < 32; i += 8)
        out[(size_t)(d0 + i) * SEQ + s0 + tx] = tile[tx][i];
}

// ---------------- layernorm (ddof=1): f32 in, bf16 out, f32 stats ----------------
__global__ __launch_bounds__(256) void layernorm_kernel(const float* __restrict__ x,
                                                        bf16* __restrict__ out,
                                                        const float* __restrict__ scale,
                                                        const float* __restrict__ shift) {
    int row = blockIdx.x;
    int t = threadIdx.x;
    const float* xr = x + (size_t)row * EMB;
    float v[4];
    float s = 0.f, s2 = 0.f;
#pragma unroll
    for (int i = 0; i < 4; i++) {
        v[i] = xr[t + 256 * i];
        s += v[i];
        s2 += v[i] * v[i];
    }
#pragma unroll
    for (int off = 32; off > 0; off >>= 1) {
        s += __shfl_down(s, off);
        s2 += __shfl_down(s2, off);
    }
    __shared__ float sh[8];
    __shared__ float stats[2];
    int lane = t & 63, wid = t >> 6;
    if (lane == 0) { sh[wid] = s; sh[wid + 4] = s2; }
    __syncthreads();
    if (t == 0) {
        float ts = sh[0] + sh[1] + sh[2] + sh[3];
        float ts2 = sh[4] + sh[5] + sh[6] + sh[7];
        float mean = ts / (float)EMB;
        float var = (ts2 - (float)EMB * mean * mean) / (float)(EMB - 1);
        stats[0] = mean;
        stats[1] = rsqrtf(var + 1e-5f);
    }
    __syncthreads();
    float mean = stats[0], inv = stats[1];
#pragma unroll
    for (int i = 0; i < 4; i++) {
        int c = t + 256 * i;
        float y = (v[i] - mean) * inv * scale[c] + shift[c];
        out[(size_t)row * EMB + c] = (bf16)y;
    }
}

// For gemm64 (TM=TN=64 over M=4096,N=1024): NYB=64, NXB=16, grid=1024.
__device__ __forceinline__ void swz64(int id, int& bx, int& by) {
    int xcd = id & 7, m = id >> 3;
    by = xcd + 8 * (m & 3) + 32 * (m >> 6);
    bx = (m >> 2) & 15;
}

// stage one 128x64 (bf16) half-tile: 512 threads x 2 x 16B, linear LDS dest,
// global source pre-swizzled (inverse of the read-side XOR swizzle)
__device__ __forceinline__ void stage_half(const bf16* g, bf16* lds, int tid, size_t rowK64) {
    load_lds16(g, lds + tid * 8);
    load_lds16(g + rowK64, lds + 4096 + tid * 8);
}

// ---------------- 256x256 deep-pipelined GEMM (8-phase style) ----------------
template <int ACT, int QKV>
__global__ __launch_bounds__(512, 2) void gemm256_kernel(
    const bf16* __restrict__ A, const bf16* __restrict__ BT,
    bf16* __restrict__ C0, bf16* __restrict__ C1, bf16* __restrict__ C2,
    const float* __restrict__ bias0, const float* __restrict__ bias1,
    const float* __restrict__ bias2, int N, int K) {
    __shared__ __align__(16) bf16 lA[4][128 * 64];
    __shared__ __align__(16) bf16 lB[4][128 * 64];
    const int tid = threadIdx.x;
    const int wave = tid >> 6, lane = tid & 63;
    const int an = lane & 15, aq = lane >> 4;
    const int wr = wave >> 2, wc = wave & 3;

    int id = blockIdx.x;
    int xcd = id & 7, m = id >> 3;
    int by = xcd * 2 + (m & 1);
    int bx = m >> 1;
    int m0 = by * 256, n0 = bx * 256;

    const int srow = tid >> 3;                       // 0..63
    const int csw = ((tid & 7) ^ (srow & 7)) * 8;    // swizzled col offset (elems)
    const bf16* Ag = A + (size_t)(m0 + srow) * K + csw;
    const bf16* Bg = BT + (size_t)(n0 + srow) * K + csw;
    const size_t rowK64 = (size_t)64 * K;
    const size_t rowK128 = (size_t)128 * K;

    stage_half(Bg, lB[0], tid, rowK64);
    stage_half(Bg + rowK128, lB[1], tid, rowK64);
    stage_half(Ag, lA[0], tid, rowK64);
    stage_half(Ag + rowK128, lA[1], tid, rowK64);
    stage_half(Bg + 64, lB[2], tid, rowK64);
    stage_half(Bg + rowK128 + 64, lB[3], tid, rowK64);
    asm volatile("s_waitcnt vmcnt(4)" ::: "memory");
    __builtin_amdgcn_s_barrier();

    f32x4 acc[8][4] = {};
    const int NT = K >> 6;
    const int lrB = (wc & 1) * 64;

    for (int t = 0; t < NT; ++t) {
        const bf16* As = lA[(2 * t + wr) & 3];
        const bf16* Bs = lB[(2 * t + (wc >> 1)) & 3];
        bf16x8 bfv[4][2];
#pragma unroll
        for (int p = 0; p < 4; ++p) {
            bf16x8 af[2][2];
            if (p == 0) {
#pragma unroll
                for (int j = 0; j < 4; ++j)
#pragma unroll
                    for (int kk = 0; kk < 2; ++kk) {
                        int r = lrB + 16 * j + an;
                        bfv[j][kk] = *(const bf16x8*)(Bs + r * 64 + ((kk * 4 + aq) ^ (r & 7)) * 8);
                    }
            }
#pragma unroll
            for (int ii = 0; ii < 2; ++ii)
#pragma unroll
                for (int kk = 0; kk < 2; ++kk) {
                    int r = 16 * (2 * p + ii) + an;
                    af[ii][kk] = *(const bf16x8*)(As + r * 64 + ((kk * 4 + aq) ^ (r & 7)) * 8);
                }
            if (p == 0) {
                if (t + 1 < NT)
                    stage_half(Ag + (size_t)(t + 1) * 64, lA[(2 * t + 2) & 3], tid, rowK64);
            } else if (p == 1) {
                if (t + 1 < NT)
                    stage_half(Ag + rowK128 + (size_t)(t + 1) * 64, lA[(2 * t + 3) & 3], tid, rowK64);
            } else if (p == 2) {
                if (t + 2 < NT)
                    stage_half(Bg + (size_t)(t + 2) * 64, lB[(2 * t + 4) & 3], tid, rowK64);
            } else {
                if (t + 2 < NT) {
                    stage_half(Bg + rowK128 + (size_t)(t + 2) * 64, lB[(2 * t + 5) & 3], tid, rowK64);
                    asm volatile("s_waitcnt vmcnt(4)" ::: "memory");
                } else {
                    asm volatile("s_waitcnt vmcnt(0)" ::: "memory");
                }
            }
            __builtin_amdgcn_s_barrier();
            asm volatile("s_waitcnt lgkmcnt(0)" ::: "memory");
            __builtin_amdgcn_s_setprio(1);
#pragma unroll
            for (int ii = 0; ii < 2; ++ii)
#pragma unroll
                for (int j = 0; j < 4; ++j)
#pragma unroll
                    for (int kk = 0; kk < 2; ++kk)
                        acc[2 * p + ii][j] = __builtin_amdgcn_mfma_f32_16x16x32_bf16(
                            af[ii][kk], bfv[j][kk], acc[2 * p + ii][j], 0, 0, 0);
            __builtin_amdgcn_s_setprio(0);
            __builtin_amdgcn_s_barrier();
        }
    }

#pragma unroll
    for (int j = 0; j < 4; ++j) {
        int col = n0 + wc * 64 + 16 * j + an;
        if (QKV == 0) {
            float bv = bias0[col];
#pragma unroll
            for (int i = 0; i < 8; ++i) {
#pragma unroll
                for (int r = 0; r < 4; ++r) {
                    int row = m0 + wr * 128 + 16 * i + aq * 4 + r;
                    float v = acc[i][j][r] + bv;
                    if (ACT == 1) v = gelu_f(v);
                    C0[(size_t)row * N + col] = (bf16)v;
                }
            }
        } else {
            int region = col >> 10, c = col & 1023;
            const float* bp = (region == 0) ? bias0 : (region == 1) ? bias1 : bias2;
            bf16* outp = (region == 0) ? C0 : (region == 1) ? C1 : C2;
            float scl = (region == 0) ? 0.125f : 1.0f;
            float bv = bp[c];
#pragma unroll
            for (int i = 0; i < 8; ++i) {
#pragma unroll
                for (int r = 0; r < 4; ++r) {
                    int row = m0 + wr * 128 + 16 * i + aq * 4 + r;
                    float v = (acc[i][j][r] + bv) * scl;
                    outp[(size_t)row * EMB + c] = (bf16)v;
                }
            }
        }
    }
}

// ---------------- 64x64 GEMM, BK=64, double-buffered, swizzled (M=4096,N=1024) ----------------
template <int RES, int OUTF>
__global__ __launch_bounds__(256) void gemm64_kernel(const bf16* __restrict__ A,
                                                     const bf16* __restrict__ BT,
                                                     void* __restrict__ Cout,
                                                     const float* __restrict__ bias,
                                                     const float* __restrict__ res,
                                                     int M, int N, int K) {
    __shared__ __align__(16) bf16 lA[2][2][64 * 32];   // [buf][k-half][row][col]
    __shared__ __align__(16) bf16 lB[2][2][64 * 32];
    int tid = threadIdx.x;
    int wave = tid >> 6, lane = tid & 63;
    int bx, by;
    swz64(blockIdx.x, bx, by);
    int m0 = by * 64, n0 = bx * 64;
    int wm = (wave >> 1) * 32, wn = (wave & 1) * 32;
    f32x4 acc[2][2] = {};

    int srow = wave * 16 + (lane >> 2);
    int skc = (lane & 3) * 8;
    const bf16* Ag = A + (size_t)(m0 + srow) * K + skc;
    const bf16* Bg = BT + (size_t)(n0 + srow) * K + skc;
    size_t woff = (size_t)(wave * 16) * 32;

    const int an = lane & 15;
    const int ak = (lane >> 4) * 8;

    load_lds16(Ag, &lA[0][0][woff]);
    load_lds16(Ag + 32, &lA[0][1][woff]);
    load_lds16(Bg, &lB[0][0][woff]);
    load_lds16(Bg + 32, &lB[0][1][woff]);

    int nsteps = K >> 6;
    for (int t = 0; t < nsteps; t++) {
        int buf = t & 1;
        asm volatile("s_waitcnt vmcnt(0)" ::: "memory");
        __syncthreads();
        if (t + 1 < nsteps) {
            int k0 = (t + 1) * 64;
            load_lds16(Ag + k0, &lA[buf ^ 1][0][woff]);
            load_lds16(Ag + k0 + 32, &lA[buf ^ 1][1][woff]);
            load_lds16(Bg + k0, &lB[buf ^ 1][0][woff]);
            load_lds16(Bg + k0 + 32, &lB[buf ^ 1][1][woff]);
        }
#pragma unroll
        for (int h = 0; h < 2; h++) {
            bf16x8 af[2], bfv[2];
#pragma unroll
            for (int i = 0; i < 2; i++)
                af[i] = *(const bf16x8*)(&lA[buf][h][(wm + 16 * i + an) * 32 + ak]);
#pragma unroll
            for (int j = 0; j < 2; j++)
                bfv[j] = *(const bf16x8*)(&lB[buf][h][(wn + 16 * j + an) * 32 + ak]);
#pragma unroll
            for (int i = 0; i < 2; i++)
#pragma unroll
                for (int j = 0; j < 2; j++)
                    acc[i][j] = __builtin_amdgcn_mfma_f32_16x16x32_bf16(af[i], bfv[j], acc[i][j], 0, 0, 0);
        }
    }
#pragma unroll
    for (int j = 0; j < 2; j++) {
        int col = n0 + wn + 16 * j + an;
        float bv = bias[col];
#pragma unroll
        for (int i = 0; i < 2; i++) {
#pragma unroll
            for (int r = 0; r < 4; r++) {
                int row = m0 + wm + 16 * i + (lane >> 4) * 4 + r;
                float vx = acc[i][j][r] + bv;
                size_t idx = (size_t)row * N + col;
                if (RES == 2) vx += res[idx];
                if (OUTF == 0) ((bf16*)Cout)[idx] = (bf16)vx;
                else ((float*)Cout)[idx] = vx;
            }
        }
    }
}

// ---------------- causal flash attention, KVBLK=64, pair-balanced schedule ----------------
// Causal work per q-tile bx is bx+1 KV-steps (1..32): naive 1-tile-per-block grids
// are TAIL-BOUND (R9: Occupancy 10.7%, worst CU ~122 step-units vs avg ~70).
// Fix: each block processes the pair {bx, 31-bx} sequentially -> exactly 33 steps
// per block, perfectly balanced. Inner structure identical to the verified R3
// kernel (XOR-swizzled K/V LDS, wave-private pbuf, split-out masked last step).
// Grid 512 (32 bh x 16 pairs), LDS 38KB -> 4 blocks/CU capacity.
// NOTE: exp via __expf (raw inline-asm v_exp_f32 -> stale reads, R2 failure).
__global__ __launch_bounds__(256, 4) void attn_kernel(const bf16* __restrict__ q,
                                                      const bf16* __restrict__ k,
                                                      const bf16* __restrict__ vt,
                                                      bf16* __restrict__ ctx) {
    __shared__ __align__(16) bf16 ksm[2][64 * 64];
    __shared__ __align__(16) bf16 vsm[2][64 * 64];
    __shared__ __align__(16) bf16 pbuf[4][16][40];   // per-wave P half-tile (32 kv)
    int tid = threadIdx.x;
    int wave = tid >> 6, lane = tid & 63;
    int id = blockIdx.x;
    int bh = id >> 4;                    // 0..31
    int pr = ((id & 15) + bh) & 15;      // pair index, swizzled per head
    int b = bh >> 4, h = bh & 15;
    const bf16* qp = q + (size_t)b * SEQ * EMB + h * HDIM;
    const bf16* kp = k + (size_t)b * SEQ * EMB + h * HDIM;
    const bf16* vp = vt + (size_t)bh * HDIM * SEQ;

    int an = lane & 15, aq = lane >> 4;

    int srow0 = tid >> 3;           // 0..31
    int srow1 = srow0 + 32;         // 32..63
    int sc = tid & 7;
    const bf16* kg0 = kp + (size_t)srow0 * EMB + ((sc ^ (srow0 & 7)) * 8);
    const bf16* kg1 = kp + (size_t)srow1 * EMB + ((sc ^ (srow1 & 7)) * 8);
    const bf16* vg0 = vp + (size_t)srow0 * SEQ + ((sc ^ (srow0 & 7)) * 8);
    const bf16* vg1 = vp + (size_t)srow1 * SEQ + ((sc ^ (srow1 & 7)) * 8);

    for (int g = 0; g < 2; g++) {
        int bx = g ? 31 - pr : pr;
        int q0 = bx * 64 + wave * 16;
        int nsteps = bx + 1;

        bf16x8 qf0 = *(const bf16x8*)(qp + (size_t)(q0 + an) * EMB + aq * 8);
        bf16x8 qf1 = *(const bf16x8*)(qp + (size_t)(q0 + an) * EMB + 32 + aq * 8);
        f32x4 o[4] = {};
        float lp[4] = {0.f, 0.f, 0.f, 0.f};

        // phase 1 restages ksm[0]/vsm[0]: wait for all waves' phase-0 LDS reads
        if (g) __syncthreads();

        load_lds16(kg0, ksm[0] + tid * 8);
        load_lds16(kg1, ksm[0] + (256 + tid) * 8);
        load_lds16(vg0, vsm[0] + tid * 8);
        load_lds16(vg1, vsm[0] + (256 + tid) * 8);
        asm volatile("s_waitcnt vmcnt(0)" ::: "memory");
        __syncthreads();

        auto step = [&](int t, bool last_) {
            int buf = t & 1;
            if (!last_) {
                size_t ko = (size_t)(t + 1) * 64 * EMB;
                int vo = (t + 1) * 64;
                load_lds16(kg0 + ko, ksm[buf ^ 1] + tid * 8);
                load_lds16(kg1 + ko, ksm[buf ^ 1] + (256 + tid) * 8);
                load_lds16(vg0 + vo, vsm[buf ^ 1] + tid * 8);
                load_lds16(vg1 + vo, vsm[buf ^ 1] + (256 + tid) * 8);
            }
            const bf16* kb = ksm[buf];
            const bf16* vb = vsm[buf];
            int kvbase = t * 64;
#pragma unroll
            for (int hh = 0; hh < 2; hh++) {
#pragma unroll
                for (int nbl = 0; nbl < 2; nbl++) {
                    int nb = hh * 2 + nbl;
                    int krow = nb * 16 + an;
                    bf16x8 kfa = *(const bf16x8*)(kb + krow * 64 + ((aq ^ (an & 7)) * 8));
                    bf16x8 kfb = *(const bf16x8*)(kb + krow * 64 + (((4 + aq) ^ (an & 7)) * 8));
                    f32x4 s = {};
                    s = __builtin_amdgcn_mfma_f32_16x16x32_bf16(qf0, kfa, s, 0, 0, 0);
                    s = __builtin_amdgcn_mfma_f32_16x16x32_bf16(qf1, kfb, s, 0, 0, 0);
                    int kvg = kvbase + nb * 16 + an;
#pragma unroll
                    for (int r = 0; r < 4; r++) {
                        float p = __expf(s[r]);
                        if (last_ && (kvg > q0 + aq * 4 + r)) p = 0.f;
                        lp[r] += p;
                        pbuf[wave][aq * 4 + r][nbl * 16 + an] = (bf16)p;
                    }
                }
                asm volatile("s_waitcnt lgkmcnt(0)" ::: "memory");
                bf16x8 pa = *(const bf16x8*)(&pbuf[wave][an][aq * 8]);
#pragma unroll
                for (int dt = 0; dt < 4; dt++) {
                    int drow = dt * 16 + an;
                    bf16x8 vf = *(const bf16x8*)(vb + drow * 64 + (((hh * 4 + aq) ^ (an & 7)) * 8));
                    o[dt] = __builtin_amdgcn_mfma_f32_16x16x32_bf16(pa, vf, o[dt], 0, 0, 0);
                }
            }
            if (!last_) {
                asm volatile("s_waitcnt vmcnt(0)" ::: "memory");
                __syncthreads();
            }
        };

        for (int t = 0; t < nsteps - 1; t++) step(t, false);
        step(nsteps - 1, true);

#pragma unroll
        for (int r = 0; r < 4; r++) {
            float v = lp[r];
            v += __shfl_xor(v, 1);
            v += __shfl_xor(v, 2);
            v += __shfl_xor(v, 4);
            v += __shfl_xor(v, 8);
            lp[r] = v;
        }
#pragma unroll
        for (int dt = 0; dt < 4; dt++) {
#pragma unroll
            for (int r = 0; r < 4; r++) {
                int row = q0 + aq * 4 + r;
                int col = h * HDIM + dt * 16 + an;
                ctx[((size_t)b * SEQ + row) * EMB + col] = (bf16)(o[dt][r] / lp[r]);
            }
        }
    }
}

extern "C" void kernel_launch(void* const* d_in, const int* in_sizes, int n_in,
                              void* d_out, int out_size, void* d_ws, size_t ws_size,
                              hipStream_t stream) {
    const float* x = (const float*)d_in[0];
    const float* Wq = (const float*)d_in[1];
    const float* bq = (const float*)d_in[2];
    const float* Wk = (const float*)d_in[3];
    const float* bk = (const float*)d_in[4];
    const float* Wv = (const float*)d_in[5];
    const float* bv = (const float*)d_in[6];
    const float* Wo = (const float*)d_in[7];
    const float* bo = (const float*)d_in[8];
    const float* W1 = (const float*)d_in[9];
    const float* b1 = (const float*)d_in[10];
    const float* W2 = (const float*)d_in[11];
    const float* b2 = (const float*)d_in[12];
    const float* ln1s = (const float*)d_in[13];
    const float* ln1b = (const float*)d_in[14];
    const float* ln2s = (const float*)d_in[15];
    const float* ln2b = (const float*)d_in[16];
    float* out = (float*)d_out;

    char* ws = (char*)d_ws;
    const size_t MB = 1ull << 20;
    bf16* WqT = (bf16*)(ws + 0 * MB);    // WqT/WkT/WvT contiguous = [3072][1024]
    bf16* WkT = (bf16*)(ws + 2 * MB);
    bf16* WvT = (bf16*)(ws + 4 * MB);
    bf16* WoT = (bf16*)(ws + 6 * MB);
    bf16* W1T = (bf16*)(ws + 8 * MB);    // [4096][1024]
    bf16* W2T = (bf16*)(ws + 16 * MB);   // [1024][4096]
    bf16* hbuf = (bf16*)(ws + 24 * MB);
    bf16* qbuf = (bf16*)(ws + 32 * MB);
    bf16* kbuf = (bf16*)(ws + 40 * MB);
    bf16* vbuf = (bf16*)(ws + 48 * MB);
    bf16* vtb = (bf16*)(ws + 56 * MB);
    bf16* ctxb = (bf16*)(ws + 64 * MB);
    float* x1 = (float*)(ws + 72 * MB);  // fp32 residual, 16MB
    bf16* hff = (bf16*)(ws + 32 * MB);   // overlaps q/k/v/vt (dead by FFN)

    dim3 tb(32, 8);
    transpose_cast4_kernel<<<dim3(32, 32, 4), tb, 0, stream>>>(Wq, Wk, Wv, Wo, WqT, WkT, WvT, WoT);
    transpose_cast_kernel<<<dim3(128, 32), tb, 0, stream>>>(W1, W1T, 1024, 4096);
    transpose_cast_kernel<<<dim3(32, 128), tb, 0, stream>>>(W2, W2T, 4096, 1024);

    layernorm_kernel<<<ROWS, 256, 0, stream>>>(x, hbuf, ln1s, ln1b);

    // fused QKV: 256x256 tiles, N=3072 -> grid 16*12 = 192, deep-pipelined
    gemm256_kernel<0, 1><<<192, 512, 0, stream>>>(hbuf, WqT, qbuf, kbuf, vbuf,
                                                  bq, bk, bv, EMB, EMB);

    transpose_v_kernel<<<dim3(64, 2, 32), tb, 0, stream>>>(vbuf, vtb);

    // pair-balanced causal attention: 33 KV-steps per block, grid 512
    attn_kernel<<<512, 256, 0, stream>>>(qbuf, kbuf, vtb, ctxb);

    // x1 = x + ctx @ Wo + bo   (f32 out, f32 residual) — 64x64 tiles, swizzled
    gemm64_kernel<2, 1><<<1024, 256, 0, stream>>>(ctxb, WoT, x1, bo, x, ROWS, EMB, EMB);

    layernorm_kernel<<<ROWS, 256, 0, stream>>>(x1, hbuf, ln2s, ln2b);

    // hff = gelu(h2 @ W1 + b1) — 256x256 tiles, N=4096 -> grid 16*16 = 256
    gemm256_kernel<1, 0><<<256, 512, 0, stream>>>(hbuf, W1T, hff, nullptr, nullptr,
                                                  b1, nullptr, nullptr, 4 * EMB, EMB);

    // out = x1 + hff @ W2 + b2   (f32 out, f32 residual) — 64x64 tiles, swizzled
    gemm64_kernel<2, 1><<<1024, 256, 0, stream>>>(hff, W2T, out, b2, x1, ROWS, EMB, 4 * EMB);
}

// Round 11
// 339.698 us; speedup vs baseline: 1.0783x; 1.0351x over previous
//
#include <hip/hip_runtime.h>
#include <hip/hip_bf16.h>

#define EMB 1024
#define SEQ 2048
#define BATCH 2
#define HEADS 16
#define HDIM 64
#define ROWS (BATCH*SEQ)   // 4096

typedef __hip_bfloat16 bf16;
typedef __bf16 bf16x8 __attribute__((ext_vector_type(8)));
typedef float f32x4 __attribute__((ext_vector_type(4)));
typedef unsigned short us4 __attribute__((ext_vector_type(4)));

#define AS1 __attribute__((address_space(1)))
#define AS3 __attribute__((address_space(3)))

__device__ __forceinline__ void load_lds16(const void* g, void* l) {
    __builtin_amdgcn_global_load_lds((const AS1 void*)g, (AS3 void*)l, 16, 0, 0);
}

// gelu_tanh(x) == x * sigmoid(2c(x + 0.044715 x^3)), c = sqrt(2/pi)
__device__ __forceinline__ float gelu_f(float x) {
    float y = 1.5957691216057308f * (x + 0.044715f * x * x * x);
    return x / (1.0f + __expf(-y));
}

__device__ __forceinline__ unsigned short bfbits(float f) {
    bf16 h = (bf16)f;
    return *(unsigned short*)&h;
}

// ---------------- unified weight transpose+cast: 6 matrices, one launch ----------------
// in[R][C] (f32) -> out[C][R] (bf16). 64x64 tiles, float4 loads (16B/lane),
// ushort4 stores (8B/lane). Tile map: bid 0..1023 = {Wq,Wk,Wv,Wo} (256 each),
// 1024..2047 = W1 (1024x4096), 2048..3071 = W2 (4096x1024). Grid 3072.
__global__ __launch_bounds__(256) void transpose6_kernel(
    const float* __restrict__ w0, const float* __restrict__ w1,
    const float* __restrict__ w2, const float* __restrict__ w3,
    const float* __restrict__ w4, const float* __restrict__ w5,
    bf16* __restrict__ o0, bf16* __restrict__ o1, bf16* __restrict__ o2,
    bf16* __restrict__ o3, bf16* __restrict__ o4, bf16* __restrict__ o5) {
    __shared__ bf16 tile[64][68];   // pad 68 -> 8B-aligned rows (136B stride)
    int bid = blockIdx.x;
    const float* in;
    bf16* out;
    int R, C, t, tcb;
    if (bid < 1024) {
        int w = bid >> 8;
        in = (w == 0) ? w0 : (w == 1) ? w1 : (w == 2) ? w2 : w3;
        out = (w == 0) ? o0 : (w == 1) ? o1 : (w == 2) ? o2 : o3;
        R = 1024; C = 1024; t = bid & 255; tcb = 4;
    } else if (bid < 2048) {
        in = w4; out = o4; R = 1024; C = 4096; t = bid - 1024; tcb = 6;
    } else {
        in = w5; out = o5; R = 4096; C = 1024; t = bid - 2048; tcb = 4;
    }
    int tr = t >> tcb, tc = t & ((1 << tcb) - 1);
    int r0 = tr * 64, c0 = tc * 64;
    int tid = threadIdx.x;
    int lr = tid >> 4, cv = tid & 15;
#pragma unroll
    for (int it = 0; it < 4; ++it) {
        int r = it * 16 + lr;
        float4 v = *(const float4*)(in + (size_t)(r0 + r) * C + c0 + 4 * cv);
        tile[r][4 * cv + 0] = (bf16)v.x;
        tile[r][4 * cv + 1] = (bf16)v.y;
        tile[r][4 * cv + 2] = (bf16)v.z;
        tile[r][4 * cv + 3] = (bf16)v.w;
    }
    __syncthreads();
#pragma unroll
    for (int it = 0; it < 4; ++it) {
        int c = it * 16 + lr;
        us4 u;
        u.x = *(unsigned short*)&tile[4 * cv + 0][c];
        u.y = *(unsigned short*)&tile[4 * cv + 1][c];
        u.z = *(unsigned short*)&tile[4 * cv + 2][c];
        u.w = *(unsigned short*)&tile[4 * cv + 3][c];
        *(us4*)((unsigned short*)out + (size_t)(c0 + c) * R + r0 + 4 * cv) = u;
    }
}

// ---------------- per-head V transpose: v[b][s][h*64+d] -> vt[(b*16+h)][d][s] (bf16) ----------------
__global__ void transpose_v_kernel(const bf16* __restrict__ v, bf16* __restrict__ vt) {
    __shared__ bf16 tile[32][33];
    int tx = threadIdx.x, ty = threadIdx.y;
    int bh = blockIdx.z;
    const bf16* in = v + (size_t)(bh >> 4) * SEQ * EMB + (bh & 15) * HDIM;
    bf16* out = vt + (size_t)bh * HDIM * SEQ;
    int s0 = blockIdx.x * 32, d0 = blockIdx.y * 32;
    for (int i = ty; i < 32; i += 8)
        tile[i][tx] = in[(size_t)(s0 + i) * EMB + d0 + tx];
    __syncthreads();
    for (int i = ty; i < 32; i += 8)
        out[(size_t)(d0 + i) * SEQ + s0 + tx] = tile[tx][i];
}

// ---------------- layernorm (ddof=1): f32 in, bf16 out, vectorized (G13) ----------------
__global__ __launch_bounds__(256) void layernorm_kernel(const float* __restrict__ x,
                                                        bf16* __restrict__ out,
                                                        const float* __restrict__ scale,
                                                        const float* __restrict__ shift) {
    int row = blockIdx.x;
    int t = threadIdx.x;
    const float* xr = x + (size_t)row * EMB;
    float4 v = *(const float4*)(xr + 4 * t);
    float s = v.x + v.y + v.z + v.w;
    float s2 = v.x * v.x + v.y * v.y + v.z * v.z + v.w * v.w;
#pragma unroll
    for (int off = 32; off > 0; off >>= 1) {
        s += __shfl_down(s, off);
        s2 += __shfl_down(s2, off);
    }
    __shared__ float sh[8];
    __shared__ float stats[2];
    int lane = t & 63, wid = t >> 6;
    if (lane == 0) { sh[wid] = s; sh[wid + 4] = s2; }
    __syncthreads();
    if (t == 0) {
        float ts = sh[0] + sh[1] + sh[2] + sh[3];
        float ts2 = sh[4] + sh[5] + sh[6] + sh[7];
        float mean = ts / (float)EMB;
        float var = (ts2 - (float)EMB * mean * mean) / (float)(EMB - 1);
        stats[0] = mean;
        stats[1] = rsqrtf(var + 1e-5f);
    }
    __syncthreads();
    float mean = stats[0], inv = stats[1];
    float4 sc = *(const float4*)(scale + 4 * t);
    float4 sf = *(const float4*)(shift + 4 * t);
    us4 u;
    u.x = bfbits((v.x - mean) * inv * sc.x + sf.x);
    u.y = bfbits((v.y - mean) * inv * sc.y + sf.y);
    u.z = bfbits((v.z - mean) * inv * sc.z + sf.z);
    u.w = bfbits((v.w - mean) * inv * sc.w + sf.w);
    *(us4*)((unsigned short*)out + (size_t)row * EMB + 4 * t) = u;
}

// For gemm64 (TM=TN=64 over M=4096,N=1024): NYB=64, NXB=16, grid=1024.
__device__ __forceinline__ void swz64(int id, int& bx, int& by) {
    int xcd = id & 7, m = id >> 3;
    by = xcd + 8 * (m & 3) + 32 * (m >> 6);
    bx = (m >> 2) & 15;
}

// stage one 128x64 (bf16) half-tile: 512 threads x 2 x 16B, linear LDS dest,
// global source pre-swizzled (inverse of the read-side XOR swizzle)
__device__ __forceinline__ void stage_half(const bf16* g, bf16* lds, int tid, size_t rowK64) {
    load_lds16(g, lds + tid * 8);
    load_lds16(g + rowK64, lds + 4096 + tid * 8);
}

// ---------------- 256x256 deep-pipelined GEMM (8-phase style) ----------------
template <int ACT, int QKV>
__global__ __launch_bounds__(512, 2) void gemm256_kernel(
    const bf16* __restrict__ A, const bf16* __restrict__ BT,
    bf16* __restrict__ C0, bf16* __restrict__ C1, bf16* __restrict__ C2,
    const float* __restrict__ bias0, const float* __restrict__ bias1,
    const float* __restrict__ bias2, int N, int K) {
    __shared__ __align__(16) bf16 lA[4][128 * 64];
    __shared__ __align__(16) bf16 lB[4][128 * 64];
    const int tid = threadIdx.x;
    const int wave = tid >> 6, lane = tid & 63;
    const int an = lane & 15, aq = lane >> 4;
    const int wr = wave >> 2, wc = wave & 3;

    int id = blockIdx.x;
    int xcd = id & 7, m = id >> 3;
    int by = xcd * 2 + (m & 1);
    int bx = m >> 1;
    int m0 = by * 256, n0 = bx * 256;

    const int srow = tid >> 3;                       // 0..63
    const int csw = ((tid & 7) ^ (srow & 7)) * 8;    // swizzled col offset (elems)
    const bf16* Ag = A + (size_t)(m0 + srow) * K + csw;
    const bf16* Bg = BT + (size_t)(n0 + srow) * K + csw;
    const size_t rowK64 = (size_t)64 * K;
    const size_t rowK128 = (size_t)128 * K;

    stage_half(Bg, lB[0], tid, rowK64);
    stage_half(Bg + rowK128, lB[1], tid, rowK64);
    stage_half(Ag, lA[0], tid, rowK64);
    stage_half(Ag + rowK128, lA[1], tid, rowK64);
    stage_half(Bg + 64, lB[2], tid, rowK64);
    stage_half(Bg + rowK128 + 64, lB[3], tid, rowK64);
    asm volatile("s_waitcnt vmcnt(4)" ::: "memory");
    __builtin_amdgcn_s_barrier();

    f32x4 acc[8][4] = {};
    const int NT = K >> 6;
    const int lrB = (wc & 1) * 64;

    for (int t = 0; t < NT; ++t) {
        const bf16* As = lA[(2 * t + wr) & 3];
        const bf16* Bs = lB[(2 * t + (wc >> 1)) & 3];
        bf16x8 bfv[4][2];
#pragma unroll
        for (int p = 0; p < 4; ++p) {
            bf16x8 af[2][2];
            if (p == 0) {
#pragma unroll
                for (int j = 0; j < 4; ++j)
#pragma unroll
                    for (int kk = 0; kk < 2; ++kk) {
                        int r = lrB + 16 * j + an;
                        bfv[j][kk] = *(const bf16x8*)(Bs + r * 64 + ((kk * 4 + aq) ^ (r & 7)) * 8);
                    }
            }
#pragma unroll
            for (int ii = 0; ii < 2; ++ii)
#pragma unroll
                for (int kk = 0; kk < 2; ++kk) {
                    int r = 16 * (2 * p + ii) + an;
                    af[ii][kk] = *(const bf16x8*)(As + r * 64 + ((kk * 4 + aq) ^ (r & 7)) * 8);
                }
            if (p == 0) {
                if (t + 1 < NT)
                    stage_half(Ag + (size_t)(t + 1) * 64, lA[(2 * t + 2) & 3], tid, rowK64);
            } else if (p == 1) {
                if (t + 1 < NT)
                    stage_half(Ag + rowK128 + (size_t)(t + 1) * 64, lA[(2 * t + 3) & 3], tid, rowK64);
            } else if (p == 2) {
                if (t + 2 < NT)
                    stage_half(Bg + (size_t)(t + 2) * 64, lB[(2 * t + 4) & 3], tid, rowK64);
            } else {
                if (t + 2 < NT) {
                    stage_half(Bg + rowK128 + (size_t)(t + 2) * 64, lB[(2 * t + 5) & 3], tid, rowK64);
                    asm volatile("s_waitcnt vmcnt(4)" ::: "memory");
                } else {
                    asm volatile("s_waitcnt vmcnt(0)" ::: "memory");
                }
            }
            __builtin_amdgcn_s_barrier();
            asm volatile("s_waitcnt lgkmcnt(0)" ::: "memory");
            __builtin_amdgcn_s_setprio(1);
#pragma unroll
            for (int ii = 0; ii < 2; ++ii)
#pragma unroll
                for (int j = 0; j < 4; ++j)
#pragma unroll
                    for (int kk = 0; kk < 2; ++kk)
                        acc[2 * p + ii][j] = __builtin_amdgcn_mfma_f32_16x16x32_bf16(
                            af[ii][kk], bfv[j][kk], acc[2 * p + ii][j], 0, 0, 0);
            __builtin_amdgcn_s_setprio(0);
            __builtin_amdgcn_s_barrier();
        }
    }

#pragma unroll
    for (int j = 0; j < 4; ++j) {
        int col = n0 + wc * 64 + 16 * j + an;
        if (QKV == 0) {
            float bv = bias0[col];
#pragma unroll
            for (int i = 0; i < 8; ++i) {
#pragma unroll
                for (int r = 0; r < 4; ++r) {
                    int row = m0 + wr * 128 + 16 * i + aq * 4 + r;
                    float v = acc[i][j][r] + bv;
                    if (ACT == 1) v = gelu_f(v);
                    C0[(size_t)row * N + col] = (bf16)v;
                }
            }
        } else {
            int region = col >> 10, c = col & 1023;
            const float* bp = (region == 0) ? bias0 : (region == 1) ? bias1 : bias2;
            bf16* outp = (region == 0) ? C0 : (region == 1) ? C1 : C2;
            float scl = (region == 0) ? 0.125f : 1.0f;
            float bv = bp[c];
#pragma unroll
            for (int i = 0; i < 8; ++i) {
#pragma unroll
                for (int r = 0; r < 4; ++r) {
                    int row = m0 + wr * 128 + 16 * i + aq * 4 + r;
                    float v = (acc[i][j][r] + bv) * scl;
                    outp[(size_t)row * EMB + c] = (bf16)v;
                }
            }
        }
    }
}

// ---------------- 64x64 GEMM, BK=64, double-buffered, swizzled (M=4096,N=1024) ----------------
template <int RES, int OUTF>
__global__ __launch_bounds__(256) void gemm64_kernel(const bf16* __restrict__ A,
                                                     const bf16* __restrict__ BT,
                                                     void* __restrict__ Cout,
                                                     const float* __restrict__ bias,
                                                     const float* __restrict__ res,
                                                     int M, int N, int K) {
    __shared__ __align__(16) bf16 lA[2][2][64 * 32];   // [buf][k-half][row][col]
    __shared__ __align__(16) bf16 lB[2][2][64 * 32];
    int tid = threadIdx.x;
    int wave = tid >> 6, lane = tid & 63;
    int bx, by;
    swz64(blockIdx.x, bx, by);
    int m0 = by * 64, n0 = bx * 64;
    int wm = (wave >> 1) * 32, wn = (wave & 1) * 32;
    f32x4 acc[2][2] = {};

    int srow = wave * 16 + (lane >> 2);
    int skc = (lane & 3) * 8;
    const bf16* Ag = A + (size_t)(m0 + srow) * K + skc;
    const bf16* Bg = BT + (size_t)(n0 + srow) * K + skc;
    size_t woff = (size_t)(wave * 16) * 32;

    const int an = lane & 15;
    const int ak = (lane >> 4) * 8;

    load_lds16(Ag, &lA[0][0][woff]);
    load_lds16(Ag + 32, &lA[0][1][woff]);
    load_lds16(Bg, &lB[0][0][woff]);
    load_lds16(Bg + 32, &lB[0][1][woff]);

    int nsteps = K >> 6;
    for (int t = 0; t < nsteps; t++) {
        int buf = t & 1;
        asm volatile("s_waitcnt vmcnt(0)" ::: "memory");
        __syncthreads();
        if (t + 1 < nsteps) {
            int k0 = (t + 1) * 64;
            load_lds16(Ag + k0, &lA[buf ^ 1][0][woff]);
            load_lds16(Ag + k0 + 32, &lA[buf ^ 1][1][woff]);
            load_lds16(Bg + k0, &lB[buf ^ 1][0][woff]);
            load_lds16(Bg + k0 + 32, &lB[buf ^ 1][1][woff]);
        }
#pragma unroll
        for (int h = 0; h < 2; h++) {
            bf16x8 af[2], bfv[2];
#pragma unroll
            for (int i = 0; i < 2; i++)
                af[i] = *(const bf16x8*)(&lA[buf][h][(wm + 16 * i + an) * 32 + ak]);
#pragma unroll
            for (int j = 0; j < 2; j++)
                bfv[j] = *(const bf16x8*)(&lB[buf][h][(wn + 16 * j + an) * 32 + ak]);
#pragma unroll
            for (int i = 0; i < 2; i++)
#pragma unroll
                for (int j = 0; j < 2; j++)
                    acc[i][j] = __builtin_amdgcn_mfma_f32_16x16x32_bf16(af[i], bfv[j], acc[i][j], 0, 0, 0);
        }
    }
#pragma unroll
    for (int j = 0; j < 2; j++) {
        int col = n0 + wn + 16 * j + an;
        float bv = bias[col];
#pragma unroll
        for (int i = 0; i < 2; i++) {
#pragma unroll
            for (int r = 0; r < 4; r++) {
                int row = m0 + wm + 16 * i + (lane >> 4) * 4 + r;
                float vx = acc[i][j][r] + bv;
                size_t idx = (size_t)row * N + col;
                if (RES == 2) vx += res[idx];
                if (OUTF == 0) ((bf16*)Cout)[idx] = (bf16)vx;
                else ((float*)Cout)[idx] = vx;
            }
        }
    }
}

// ---------------- causal flash attention, KVBLK=64, pair-balanced schedule ----------------
// Each block processes the pair {bx, 31-bx} sequentially -> exactly 33 KV-steps
// per block (R9 fix: tail-bound at Occupancy 10.7% before). Inner structure is
// the verified R3 kernel (XOR-swizzled K/V LDS, wave-private pbuf, masked last
// step). Grid 512, LDS 38KB -> 4 blocks/CU.
// NOTE: exp via __expf (raw inline-asm v_exp_f32 -> stale reads, R2 failure).
__global__ __launch_bounds__(256, 4) void attn_kernel(const bf16* __restrict__ q,
                                                      const bf16* __restrict__ k,
                                                      const bf16* __restrict__ vt,
                                                      bf16* __restrict__ ctx) {
    __shared__ __align__(16) bf16 ksm[2][64 * 64];
    __shared__ __align__(16) bf16 vsm[2][64 * 64];
    __shared__ __align__(16) bf16 pbuf[4][16][40];   // per-wave P half-tile (32 kv)
    int tid = threadIdx.x;
    int wave = tid >> 6, lane = tid & 63;
    int id = blockIdx.x;
    int bh = id >> 4;                    // 0..31
    int pr = ((id & 15) + bh) & 15;      // pair index, swizzled per head
    int b = bh >> 4, h = bh & 15;
    const bf16* qp = q + (size_t)b * SEQ * EMB + h * HDIM;
    const bf16* kp = k + (size_t)b * SEQ * EMB + h * HDIM;
    const bf16* vp = vt + (size_t)bh * HDIM * SEQ;

    int an = lane & 15, aq = lane >> 4;

    int srow0 = tid >> 3;           // 0..31
    int srow1 = srow0 + 32;         // 32..63
    int sc = tid & 7;
    const bf16* kg0 = kp + (size_t)srow0 * EMB + ((sc ^ (srow0 & 7)) * 8);
    const bf16* kg1 = kp + (size_t)srow1 * EMB + ((sc ^ (srow1 & 7)) * 8);
    const bf16* vg0 = vp + (size_t)srow0 * SEQ + ((sc ^ (srow0 & 7)) * 8);
    const bf16* vg1 = vp + (size_t)srow1 * SEQ + ((sc ^ (srow1 & 7)) * 8);

    for (int g = 0; g < 2; g++) {
        int bx = g ? 31 - pr : pr;
        int q0 = bx * 64 + wave * 16;
        int nsteps = bx + 1;

        bf16x8 qf0 = *(const bf16x8*)(qp + (size_t)(q0 + an) * EMB + aq * 8);
        bf16x8 qf1 = *(const bf16x8*)(qp + (size_t)(q0 + an) * EMB + 32 + aq * 8);
        f32x4 o[4] = {};
        float lp[4] = {0.f, 0.f, 0.f, 0.f};

        // phase 1 restages ksm[0]/vsm[0]: wait for all waves' phase-0 LDS reads
        if (g) __syncthreads();

        load_lds16(kg0, ksm[0] + tid * 8);
        load_lds16(kg1, ksm[0] + (256 + tid) * 8);
        load_lds16(vg0, vsm[0] + tid * 8);
        load_lds16(vg1, vsm[0] + (256 + tid) * 8);
        asm volatile("s_waitcnt vmcnt(0)" ::: "memory");
        __syncthreads();

        auto step = [&](int t, bool last_) {
            int buf = t & 1;
            if (!last_) {
                size_t ko = (size_t)(t + 1) * 64 * EMB;
                int vo = (t + 1) * 64;
                load_lds16(kg0 + ko, ksm[buf ^ 1] + tid * 8);
                load_lds16(kg1 + ko, ksm[buf ^ 1] + (256 + tid) * 8);
                load_lds16(vg0 + vo, vsm[buf ^ 1] + tid * 8);
                load_lds16(vg1 + vo, vsm[buf ^ 1] + (256 + tid) * 8);
            }
            const bf16* kb = ksm[buf];
            const bf16* vb = vsm[buf];
            int kvbase = t * 64;
#pragma unroll
            for (int hh = 0; hh < 2; hh++) {
#pragma unroll
                for (int nbl = 0; nbl < 2; nbl++) {
                    int nb = hh * 2 + nbl;
                    int krow = nb * 16 + an;
                    bf16x8 kfa = *(const bf16x8*)(kb + krow * 64 + ((aq ^ (an & 7)) * 8));
                    bf16x8 kfb = *(const bf16x8*)(kb + krow * 64 + (((4 + aq) ^ (an & 7)) * 8));
                    f32x4 s = {};
                    s = __builtin_amdgcn_mfma_f32_16x16x32_bf16(qf0, kfa, s, 0, 0, 0);
                    s = __builtin_amdgcn_mfma_f32_16x16x32_bf16(qf1, kfb, s, 0, 0, 0);
                    int kvg = kvbase + nb * 16 + an;
#pragma unroll
                    for (int r = 0; r < 4; r++) {
                        float p = __expf(s[r]);
                        if (last_ && (kvg > q0 + aq * 4 + r)) p = 0.f;
                        lp[r] += p;
                        pbuf[wave][aq * 4 + r][nbl * 16 + an] = (bf16)p;
                    }
                }
                asm volatile("s_waitcnt lgkmcnt(0)" ::: "memory");
                bf16x8 pa = *(const bf16x8*)(&pbuf[wave][an][aq * 8]);
#pragma unroll
                for (int dt = 0; dt < 4; dt++) {
                    int drow = dt * 16 + an;
                    bf16x8 vf = *(const bf16x8*)(vb + drow * 64 + (((hh * 4 + aq) ^ (an & 7)) * 8));
                    o[dt] = __builtin_amdgcn_mfma_f32_16x16x32_bf16(pa, vf, o[dt], 0, 0, 0);
                }
            }
            if (!last_) {
                asm volatile("s_waitcnt vmcnt(0)" ::: "memory");
                __syncthreads();
            }
        };

        for (int t = 0; t < nsteps - 1; t++) step(t, false);
        step(nsteps - 1, true);

#pragma unroll
        for (int r = 0; r < 4; r++) {
            float v = lp[r];
            v += __shfl_xor(v, 1);
            v += __shfl_xor(v, 2);
            v += __shfl_xor(v, 4);
            v += __shfl_xor(v, 8);
            lp[r] = v;
        }
#pragma unroll
        for (int dt = 0; dt < 4; dt++) {
#pragma unroll
            for (int r = 0; r < 4; r++) {
                int row = q0 + aq * 4 + r;
                int col = h * HDIM + dt * 16 + an;
                ctx[((size_t)b * SEQ + row) * EMB + col] = (bf16)(o[dt][r] / lp[r]);
            }
        }
    }
}

extern "C" void kernel_launch(void* const* d_in, const int* in_sizes, int n_in,
                              void* d_out, int out_size, void* d_ws, size_t ws_size,
                              hipStream_t stream) {
    const float* x = (const float*)d_in[0];
    const float* Wq = (const float*)d_in[1];
    const float* bq = (const float*)d_in[2];
    const float* Wk = (const float*)d_in[3];
    const float* bk = (const float*)d_in[4];
    const float* Wv = (const float*)d_in[5];
    const float* bv = (const float*)d_in[6];
    const float* Wo = (const float*)d_in[7];
    const float* bo = (const float*)d_in[8];
    const float* W1 = (const float*)d_in[9];
    const float* b1 = (const float*)d_in[10];
    const float* W2 = (const float*)d_in[11];
    const float* b2 = (const float*)d_in[12];
    const float* ln1s = (const float*)d_in[13];
    const float* ln1b = (const float*)d_in[14];
    const float* ln2s = (const float*)d_in[15];
    const float* ln2b = (const float*)d_in[16];
    float* out = (float*)d_out;

    char* ws = (char*)d_ws;
    const size_t MB = 1ull << 20;
    bf16* WqT = (bf16*)(ws + 0 * MB);    // WqT/WkT/WvT contiguous = [3072][1024]
    bf16* WkT = (bf16*)(ws + 2 * MB);
    bf16* WvT = (bf16*)(ws + 4 * MB);
    bf16* WoT = (bf16*)(ws + 6 * MB);
    bf16* W1T = (bf16*)(ws + 8 * MB);    // [4096][1024]
    bf16* W2T = (bf16*)(ws + 16 * MB);   // [1024][4096]
    bf16* hbuf = (bf16*)(ws + 24 * MB);
    bf16* qbuf = (bf16*)(ws + 32 * MB);
    bf16* kbuf = (bf16*)(ws + 40 * MB);
    bf16* vbuf = (bf16*)(ws + 48 * MB);
    bf16* vtb = (bf16*)(ws + 56 * MB);
    bf16* ctxb = (bf16*)(ws + 64 * MB);
    float* x1 = (float*)(ws + 72 * MB);  // fp32 residual, 16MB
    bf16* hff = (bf16*)(ws + 32 * MB);   // overlaps q/k/v/vt (dead by FFN)

    // all six weight transposes in one vectorized launch
    transpose6_kernel<<<3072, 256, 0, stream>>>(Wq, Wk, Wv, Wo, W1, W2,
                                                WqT, WkT, WvT, WoT, W1T, W2T);

    layernorm_kernel<<<ROWS, 256, 0, stream>>>(x, hbuf, ln1s, ln1b);

    // fused QKV: 256x256 tiles, N=3072 -> grid 16*12 = 192, deep-pipelined
    gemm256_kernel<0, 1><<<192, 512, 0, stream>>>(hbuf, WqT, qbuf, kbuf, vbuf,
                                                  bq, bk, bv, EMB, EMB);

    dim3 tb(32, 8);
    transpose_v_kernel<<<dim3(64, 2, 32), tb, 0, stream>>>(vbuf, vtb);

    // pair-balanced causal attention: 33 KV-steps per block, grid 512
    attn_kernel<<<512, 256, 0, stream>>>(qbuf, kbuf, vtb, ctxb);

    // x1 = x + ctx @ Wo + bo   (f32 out, f32 residual) — 64x64 tiles, swizzled
    gemm64_kernel<2, 1><<<1024, 256, 0, stream>>>(ctxb, WoT, x1, bo, x, ROWS, EMB, EMB);

    layernorm_kernel<<<ROWS, 256, 0, stream>>>(x1, hbuf, ln2s, ln2b);

    // hff = gelu(h2 @ W1 + b1) — 256x256 tiles, N=4096 -> grid 16*16 = 256
    gemm256_kernel<1, 0><<<256, 512, 0, stream>>>(hbuf, W1T, hff, nullptr, nullptr,
                                                  b1, nullptr, nullptr, 4 * EMB, EMB);

    // out = x1 + hff @ W2 + b2   (f32 out, f32 residual) — 64x64 tiles, swizzled
    gemm64_kernel<2, 1><<<1024, 256, 0, stream>>>(hff, W2T, out, b2, x1, ROWS, EMB, 4 * EMB);
}